// Round 17
// baseline (220.124 us; speedup 1.0000x reference)
//
#include <hip/hip_runtime.h>
#include <hip/hip_bf16.h>
#include <stdint.h>

typedef __attribute__((ext_vector_type(8))) short short8;
typedef __attribute__((ext_vector_type(4))) float f32x4;
typedef __attribute__((ext_vector_type(2))) unsigned uint32x2;

#define NSEQ 4096
#define DMODEL 1024
#define MROWS 8192   // B*N

__device__ __forceinline__ unsigned short f2bf(float f) {
  union { float f; unsigned u; } v; v.f = f;
  unsigned r = v.u + 0x7fffu + ((v.u >> 16) & 1u);
  return (unsigned short)(r >> 16);
}

// packed RNE bf16x2 via the HW instruction (identical rounding to f2bf; 1 instr vs ~10)
__device__ __forceinline__ unsigned pkc(float lo, float hi) {
  unsigned r;
  asm("v_cvt_pk_bf16_f32 %0, %1, %2" : "=v"(r) : "v"(lo), "v"(hi));
  return r;
}

__device__ __forceinline__ void gload16(const unsigned short* g, unsigned short* l) {
  __builtin_amdgcn_global_load_lds(
      (const __attribute__((address_space(1))) unsigned int*)g,
      (__attribute__((address_space(3))) unsigned int*)l, 16, 0, 0);
}

// 4-lane-group (stride-16) transpose step: from (x, y) produce the two B-operand words.
__device__ __forceinline__ void pexch(unsigned x, unsigned y, unsigned& w_lo, unsigned& w_hi) {
  uint32x2 t = __builtin_amdgcn_permlane32_swap(x, y, false, false);
  uint32x2 u = __builtin_amdgcn_permlane16_swap(t[0], t[1], false, false);
  w_lo = u[0];
  w_hi = u[1];
}

// ---------------- fp32 -> bf16 convert (vectorized) ----------------
__global__ void k_conv(const float* __restrict__ src, unsigned short* __restrict__ dst) {
  int i = (blockIdx.x * 256 + threadIdx.x) * 4;
  float4 v = *(const float4*)(src + i);
  ushort4 o;
  o.x = f2bf(v.x); o.y = f2bf(v.y); o.z = f2bf(v.z); o.w = f2bf(v.w);
  *(ushort4*)(dst + i) = o;
}

// ---------------- 4 weight converts in one dispatch; Wq gets log2e/8 folded in ----------------
__global__ void k_convw(const float* __restrict__ s0, const float* __restrict__ s1,
                        const float* __restrict__ s2, const float* __restrict__ s3,
                        unsigned short* __restrict__ dst) {
  int z = blockIdx.x >> 10;
  const float* src = (z == 0) ? s0 : (z == 1) ? s1 : (z == 2) ? s2 : s3;
  float sc = (z == 0) ? 0.18033688011112042f : 1.0f;   // (1/8)*log2(e) folded into Wq
  int i = ((blockIdx.x & 1023) * 256 + threadIdx.x) * 4;
  float4 v = *(const float4*)(src + i);
  ushort4 o;
  o.x = f2bf(v.x * sc); o.y = f2bf(v.y * sc); o.z = f2bf(v.z * sc); o.w = f2bf(v.w * sc);
  *(ushort4*)(dst + (size_t)z * 1048576 + i) = o;
}

// ---------------- RoPE tables (f32): cos/sin[pos][j], j=0..31 ----------------
__global__ void k_rope_tab(float* __restrict__ cosT, float* __restrict__ sinT) {
  int i = blockIdx.x * 256 + threadIdx.x;   // 0..131071
  int pos = i >> 5, j = i & 31;
  float invf = exp2f(-(float)j * 0.41524101186092029f);  // 10000^(-j/32)
  float ang = (float)pos * invf;
  cosT[i] = cosf(ang);
  sinT[i] = sinf(ang);
}

// ---------------- GEMM  C[M,N] = A[M,K] * B[N,K]^T  (bf16 in, mode-dependent epilogue)
// 1D grid, XCD-chunked bijective swizzle. mode: -1 => z-slice decode (0=Q rope, 1=K rope,
// 2=V -> transposed Vt store), 3 => fp32 store (LDS-transposed, coalesced float4).
__global__ __launch_bounds__(256) void k_gemm_bt(
    const unsigned short* __restrict__ A,
    const unsigned short* __restrict__ Bw,
    unsigned short* __restrict__ obf,
    unsigned short* __restrict__ Vt,
    float* __restrict__ of32,
    const float* __restrict__ cosT, const float* __restrict__ sinT,
    int K, int modeArg) {
  const int N = DMODEL;
  const int q8 = gridDim.x >> 3;
  const int wg = (blockIdx.x & 7) * q8 + (blockIdx.x >> 3);
  const int z = wg >> 9;            // 512 wgs per z-slice (8 bn x 64 bm)
  const int rr = wg & 511;
  const int bn = rr & 7, bm = rr >> 3;
  const int mode = (modeArg < 0) ? z : modeArg;
  const unsigned short* Bz = Bw + (size_t)z * DMODEL * K;
  unsigned short* oz = (obf && mode <= 1) ? (obf + (size_t)z * MROWS * DMODEL) : nullptr;

  const int t = threadIdx.x;
  const int w = t >> 6, lane = t & 63;
  const int wr = w >> 1, wc = w & 1;
  const int lr = lane & 15, lg = lane >> 4;

  __shared__ __align__(16) unsigned short SM[2][128 * 64];
  unsigned short* Al = SM[0];
  unsigned short* Bl = SM[1];

  const unsigned short* Ab = A + (size_t)bm * 128 * K;
  const unsigned short* Bb = Bz + (size_t)bn * 128 * K;
  const int trow = t >> 3, tcol = (t & 7) * 8;

  f32x4 acc[4][4] = {};

  for (int k0 = 0; k0 < K; k0 += 64) {
#pragma unroll
    for (int c = 0; c < 4; ++c) {
      gload16(Ab + (size_t)(c * 32 + trow) * K + k0 + tcol, &Al[c * 2048 + t * 8]);
      gload16(Bb + (size_t)(c * 32 + trow) * K + k0 + tcol, &Bl[c * 2048 + t * 8]);
    }
    asm volatile("s_waitcnt vmcnt(0)" ::: "memory");
    __syncthreads();
#pragma unroll
    for (int kk = 0; kk < 2; ++kk) {
      short8 af[4], bfr[4];
#pragma unroll
      for (int mi = 0; mi < 4; ++mi)
        af[mi] = *(const short8*)&Al[(wr * 64 + mi * 16 + lr) * 64 + kk * 32 + lg * 8];
#pragma unroll
      for (int ni = 0; ni < 4; ++ni)
        bfr[ni] = *(const short8*)&Bl[(wc * 64 + ni * 16 + lr) * 64 + kk * 32 + lg * 8];
#pragma unroll
      for (int mi = 0; mi < 4; ++mi)
#pragma unroll
        for (int ni = 0; ni < 4; ++ni)
          acc[mi][ni] = __builtin_amdgcn_mfma_f32_16x16x32_bf16(af[mi], bfr[ni], acc[mi][ni], 0, 0, 0);
    }
    __syncthreads();
  }

  if (mode <= 1 || mode == 3) {
    // ---- C -> LDS transpose (2 half-tiles of 64 rows), coalesced row output ----
    float* Cf = (float*)&SM[0][0];   // 64 x 128 fp32 = 32 KB (exactly Al+Bl)
#pragma unroll
    for (int half = 0; half < 2; ++half) {
      if (half) __syncthreads();
      if (wr == half) {
#pragma unroll
        for (int mi = 0; mi < 4; ++mi)
#pragma unroll
          for (int ni = 0; ni < 4; ++ni)
#pragma unroll
            for (int r = 0; r < 4; ++r) {
              int row = mi * 16 + lg * 4 + r;
              int col = (wc * 64 + ni * 16 + lr) ^ (lg << 3);   // XOR keeps writes 2-way (free)
              Cf[row * 128 + col] = acc[mi][ni][r];
            }
      }
      __syncthreads();
      int pr = t >> 2;
      int gm = bm * 128 + half * 64 + pr;
      int xorv = ((pr >> 2) & 3) << 3;
      if (mode == 3) {
        float* orow = of32 + (size_t)gm * N + bn * 128;
#pragma unroll
        for (int k = 0; k < 4; ++k) {
          int c0 = (t & 3) * 8 + k * 32;
          int cs = c0 ^ xorv;
          float4 va = *(const float4*)&Cf[pr * 128 + cs];
          float4 vb = *(const float4*)&Cf[pr * 128 + cs + 4];
          *(float4*)(orow + c0) = va;
          *(float4*)(orow + c0 + 4) = vb;
        }
      } else {
        int pos = gm & (NSEQ - 1);
        const float* cB = cosT + pos * 32;
        const float* sB = sinT + pos * 32;
        unsigned short* orow = oz + (size_t)gm * N + bn * 128;
#pragma unroll
        for (int k = 0; k < 4; ++k) {
          int c0 = (t & 3) * 8 + k * 32;          // logical col (8 cols = 4 rope pairs)
          int cs = c0 ^ xorv;
          float4 va = *(const float4*)&Cf[pr * 128 + cs];
          float4 vb = *(const float4*)&Cf[pr * 128 + cs + 4];
          int j0 = (c0 & 63) >> 1;
          float4 cv = *(const float4*)&cB[j0];
          float4 sv = *(const float4*)&sB[j0];
          uint4 o;
          o.x = pkc(va.x * cv.x - va.y * sv.x, va.x * sv.x + va.y * cv.x);
          o.y = pkc(va.z * cv.y - va.w * sv.y, va.z * sv.y + va.w * cv.y);
          o.z = pkc(vb.x * cv.z - vb.y * sv.z, vb.x * sv.z + vb.y * cv.z);
          o.w = pkc(vb.z * cv.w - vb.w * sv.w, vb.z * sv.w + vb.w * cv.w);
          *(uint4*)(orow + c0) = o;
        }
      }
    }
  } else {
    // mode 2: fused V^T store: lane's 4 regs are 4 consecutive n at fixed channel gn
#pragma unroll
    for (int mi = 0; mi < 4; ++mi)
#pragma unroll
      for (int ni = 0; ni < 4; ++ni) {
        int gm0 = bm * 128 + wr * 64 + mi * 16 + lg * 4;
        int gn = bn * 128 + wc * 64 + ni * 16 + lr;
        int b = gm0 >> 12, n = gm0 & (NSEQ - 1);
        int h = gn >> 6, d = gn & 63;
        uint2 u;
        u.x = pkc(acc[mi][ni][0], acc[mi][ni][1]);
        u.y = pkc(acc[mi][ni][2], acc[mi][ni][3]);
        *(uint2*)(Vt + ((size_t)((b * 16 + h) * 64 + d)) * NSEQ + n) = u;
      }
  }
}

// ---------------- causal flash attention, swapped-operand (S^T / O^T), fixed-max ----------------
// R17 = R16 with the kv loop manually unrolled by 2 (static buffer index -> all 32 swizzled
// LDS frag reads become base-VGPR + compile-time offset: immediates; buf1 = +32768 fits the
// 16-bit ds offset field), and the 4 unnecessary epilogue __syncthreads removed (Pl is
// per-wave; wave-internal lgkmcnt ordering suffices; restage safety comes from the kv-loop's
// final barrier). Grid 512 uniform pairs (qt = 31-pq then pq), 4 waves x 32 q, KVBLK=64
// double-buffered, in-register P relayout (permlane), cvt_pk packing.
// Softmax: P = exp2(S), no max subtraction (|S|<~26 << 127 f32-exp2 headroom; masked -1e30 -> 0).
// l via ones-A MFMA.
__global__ __launch_bounds__(256, 2) void k_attn13(
    const unsigned short* __restrict__ Qb,
    const unsigned short* __restrict__ Kb,
    const unsigned short* __restrict__ Vtg,
    unsigned short* __restrict__ AO) {
  const int id = blockIdx.x;
  const int bh = id & 31;
  const int pq = id >> 5;            // 0..15
  const int b = bh >> 4, h = bh & 15;
  const int t = threadIdx.x;
  const int w = t >> 6, lane = t & 63;
  const int lr = lane & 15, hi4 = lane >> 4;
  const size_t rowbase = (size_t)b * NSEQ;

  __shared__ __align__(16) unsigned short Kl[2][64 * 64];
  __shared__ __align__(16) unsigned short Vl[2][64 * 64];
  __shared__ __align__(16) unsigned short Pl[4][16 * 64];   // epilogue-only

  const int pswz = (lr & 7) << 3;

  short8 ones;
#pragma unroll
  for (int i = 0; i < 8; ++i) ones[i] = (short)0x3F80;   // bf16 1.0

#define STAGE(buf, kv0)                                                                   \
  {                                                                                       \
    _Pragma("unroll")                                                                     \
    for (int it = 0; it < 2; ++it) {                                                      \
      int c = t + it * 256;                                                               \
      int row = c >> 3, sg = (c & 7) ^ (row & 7);                                         \
      gload16(Kb + (rowbase + (kv0) + row) * DMODEL + h * 64 + sg * 8, &Kl[buf][c * 8]);  \
      gload16(Vtg + ((size_t)bh * 64 + row) * NSEQ + (kv0) + sg * 8, &Vl[buf][c * 8]);    \
    }                                                                                     \
  }

// full per-tile compute with STATIC buffer index BUF (addresses fold to offset: immediates)
#define TILE(BUF, KV0)                                                                               \
  {                                                                                                  \
    short8 Kf[4][2], Vf[2][4];                                                                       \
    _Pragma("unroll")                                                                                \
    for (int t4 = 0; t4 < 4; ++t4)                                                                   \
      _Pragma("unroll")                                                                              \
      for (int s = 0; s < 2; ++s)                                                                    \
        Kf[t4][s] = *(const short8*)&Kl[BUF][(t4 * 16 + lr) * 64 + (((s * 4 + hi4) ^ (lr & 7)) * 8)];\
    _Pragma("unroll")                                                                                \
    for (int c = 0; c < 2; ++c)                                                                      \
      _Pragma("unroll")                                                                              \
      for (int dt = 0; dt < 4; ++dt)                                                                 \
        Vf[c][dt] = *(const short8*)&Vl[BUF][(dt * 16 + lr) * 64 + (((c * 4 + hi4) ^ (lr & 7)) * 8)];\
    _Pragma("unroll")                                                                                \
    for (int sub = 0; sub < 2; ++sub) {                                                              \
      const int qs = q0w + sub * 16;                                                                 \
      const int qlane = qs + lr;                                                                     \
      f32x4 sa[4];                                                                                   \
      const f32x4 zz = {0.f, 0.f, 0.f, 0.f};                                                         \
      __builtin_amdgcn_s_setprio(1);                                                                 \
      _Pragma("unroll")                                                                              \
      for (int t4 = 0; t4 < 4; ++t4) {                                                               \
        f32x4 x = __builtin_amdgcn_mfma_f32_16x16x32_bf16(Kf[t4][0], qf[sub][0], zz, 0, 0, 0);       \
        sa[t4] = __builtin_amdgcn_mfma_f32_16x16x32_bf16(Kf[t4][1], qf[sub][1], x, 0, 0, 0);         \
      }                                                                                              \
      __builtin_amdgcn_s_setprio(0);                                                                 \
      if ((KV0) + 63 > qs) {                                                                         \
        _Pragma("unroll")                                                                            \
        for (int t4 = 0; t4 < 4; ++t4)                                                               \
          _Pragma("unroll")                                                                          \
          for (int r = 0; r < 4; ++r)                                                                \
            if ((KV0) + t4 * 16 + hi4 * 4 + r > qlane) sa[t4][r] = -1e30f;                           \
      }                                                                                              \
      _Pragma("unroll")                                                                              \
      for (int t4 = 0; t4 < 4; ++t4)                                                                 \
        _Pragma("unroll")                                                                            \
        for (int r = 0; r < 4; ++r)                                                                  \
          sa[t4][r] = __builtin_amdgcn_exp2f(sa[t4][r]);                                             \
    unsigned a0 = pkc(sa[0][0], sa[0][1]), a1 = pkc(sa[0][2], sa[0][3]);                             \
    unsigned a2 = pkc(sa[1][0], sa[1][1]), a3 = pkc(sa[1][2], sa[1][3]);                             \
    unsigned a4 = pkc(sa[2][0], sa[2][1]), a5 = pkc(sa[2][2], sa[2][3]);                             \
    unsigned a6 = pkc(sa[3][0], sa[3][1]), a7 = pkc(sa[3][2], sa[3][3]);                             \
    unsigned w0, w1, w2, w3, x0, x1, x2, x3;                                                         \
    pexch(a0, a2, w0, w2);                                                                           \
    pexch(a1, a3, w1, w3);                                                                           \
    pexch(a4, a6, x0, x2);                                                                           \
    pexch(a5, a7, x1, x3);                                                                           \
    union { uint4 u; short8 s; } P0, P1;                                                             \
    P0.u.x = w0; P0.u.y = w1; P0.u.z = w2; P0.u.w = w3;                                              \
    P1.u.x = x0; P1.u.y = x1; P1.u.z = x2; P1.u.w = x3;                                              \
    short8 pf0 = P0.s;                                                                               \
    short8 pf1 = P1.s;                                                                               \
    __builtin_amdgcn_s_setprio(1);                                                                   \
    _Pragma("unroll")                                                                                \
    for (int dt = 0; dt < 4; ++dt) {                                                                 \
      oacc[sub][dt] = __builtin_amdgcn_mfma_f32_16x16x32_bf16(Vf[0][dt], pf0, oacc[sub][dt], 0, 0, 0);\
      oacc[sub][dt] = __builtin_amdgcn_mfma_f32_16x16x32_bf16(Vf[1][dt], pf1, oacc[sub][dt], 0, 0, 0);\
    }                                                                                                \
    lacc[sub] = __builtin_amdgcn_mfma_f32_16x16x32_bf16(ones, pf0, lacc[sub], 0, 0, 0);              \
    lacc[sub] = __builtin_amdgcn_mfma_f32_16x16x32_bf16(ones, pf1, lacc[sub], 0, 0, 0);              \
    __builtin_amdgcn_s_setprio(0);                                                                   \
    }                                                                                                \
  }

#pragma unroll
  for (int qi = 0; qi < 2; ++qi) {
    const int qt = qi ? pq : (31 - pq);
    const int q0w = qt * 128 + w * 32;

    short8 qf[2][2];
#pragma unroll
    for (int sub = 0; sub < 2; ++sub) {
      const unsigned short* qp = Qb + (rowbase + q0w + sub * 16 + lr) * DMODEL + h * 64 + hi4 * 8;
#pragma unroll
      for (int s = 0; s < 2; ++s)
        qf[sub][s] = *(const short8*)(qp + s * 32);
    }

    f32x4 oacc[2][4] = {};
    f32x4 lacc[2] = {};
    const int nkv = (qt + 1) * 2;   // always even

    STAGE(0, 0);
    asm volatile("s_waitcnt vmcnt(0)" ::: "memory");
    __syncthreads();

    for (int ib = 0; ib < nkv; ib += 2) {
      const int kv0 = ib * 64;
      // tile ib (buf 0); prefetch tile ib+1 into buf 1
      STAGE(1, kv0 + 64);
      if (kv0 <= q0w + 31) TILE(0, kv0);
      asm volatile("s_waitcnt vmcnt(0)" ::: "memory");
      __syncthreads();
      // tile ib+1 (buf 1); prefetch tile ib+2 into buf 0
      if (ib + 2 < nkv) STAGE(0, kv0 + 128);
      if (kv0 + 64 <= q0w + 31) TILE(1, kv0 + 64);
      asm volatile("s_waitcnt vmcnt(0)" ::: "memory");
      __syncthreads();
    }

    // epilogue: O^T/l -> per-wave LDS transpose (swizzled) -> coalesced bf16 stores.
    // No __syncthreads needed: Pl[w] is wave-private; lgkmcnt orders within the wave.
#pragma unroll
    for (int sub = 0; sub < 2; ++sub) {
      float inv = 1.f / lacc[sub][0];
#pragma unroll
      for (int dt = 0; dt < 4; ++dt) {
        uint2 u;
        u.x = pkc(oacc[sub][dt][0] * inv, oacc[sub][dt][1] * inv);
        u.y = pkc(oacc[sub][dt][2] * inv, oacc[sub][dt][3] * inv);
        *(uint2*)&Pl[w][lr * 64 + ((dt * 16 + hi4 * 4) ^ pswz)] = u;
      }
      asm volatile("s_waitcnt lgkmcnt(0)" ::: "memory");
      __builtin_amdgcn_sched_barrier(0);
      int q2 = lane >> 2, ch = (lane & 3) * 16;
      int qswz = (q2 & 7) << 3;
      uint4 r0 = *(const uint4*)&Pl[w][q2 * 64 + (ch ^ qswz)];
      uint4 r1 = *(const uint4*)&Pl[w][q2 * 64 + ((ch + 8) ^ qswz)];
      unsigned short* op = AO + (rowbase + q0w + sub * 16 + q2) * DMODEL + h * 64 + ch;
      *(uint4*)op = r0;
      *(uint4*)(op + 8) = r1;
      asm volatile("s_waitcnt lgkmcnt(0)" ::: "memory");
      __builtin_amdgcn_sched_barrier(0);
    }
  }
}

extern "C" void kernel_launch(void* const* d_in, const int* in_sizes, int n_in,
                              void* d_out, int out_size, void* d_ws, size_t ws_size,
                              hipStream_t stream) {
  const float* x  = (const float*)d_in[0];
  const float* Wq = (const float*)d_in[1];
  const float* Wk = (const float*)d_in[2];
  const float* Wv = (const float*)d_in[3];
  const float* Wo = (const float*)d_in[4];
  float* out = (float*)d_out;
  char* ws = (char*)d_ws;

  // ws layout (bytes):
  unsigned short* xb  = (unsigned short*)(ws);                 // 16 MB
  unsigned short* Wb  = (unsigned short*)(ws + 16777216);      // 4 x 2 MB (q,k,v,o)
  unsigned short* Qb  = (unsigned short*)(ws + 25165824);      // 16 MB
  unsigned short* Kb  = Qb + 8388608;                          // 16 MB @ 41943040
  unsigned short* Vtg = (unsigned short*)(ws + 58720256);      // 16 MB (V^T [bh*64+d][n])
  unsigned short* AO  = (unsigned short*)(ws + 75497472);      // 16 MB
  float* cosT = (float*)(ws + 92274688);                       // 512 KB
  float* sinT = (float*)(ws + 92798976);                       // 512 KB

  k_conv<<<8192, 256, 0, stream>>>(x, xb);
  k_convw<<<4096, 256, 0, stream>>>(Wq, Wk, Wv, Wo, Wb);
  k_rope_tab<<<512, 256, 0, stream>>>(cosT, sinT);

  // fused Q/K/V projections (+RoPE; scale folded into Wq), bf16 out; V stored transposed to Vtg
  k_gemm_bt<<<1536, 256, 0, stream>>>(xb, Wb, Qb, Vtg, nullptr, cosT, sinT, DMODEL, -1);

  // causal flash attention (uniform pairs, static-buffer unrolled loop, in-register P exchange)
  k_attn13<<<512, 256, 0, stream>>>(Qb, Kb, Vtg, AO);

  // output projection, fp32 out
  k_gemm_bt<<<512, 256, 0, stream>>>(AO, Wb + 3145728, nullptr, nullptr, out, cosT, sinT, DMODEL, 3);
}

// Round 18
// 219.954 us; speedup vs baseline: 1.0008x; 1.0008x over previous
//
#include <hip/hip_runtime.h>
#include <hip/hip_bf16.h>
#include <stdint.h>

typedef __attribute__((ext_vector_type(8))) short short8;
typedef __attribute__((ext_vector_type(4))) float f32x4;
typedef __attribute__((ext_vector_type(2))) unsigned uint32x2;

#define NSEQ 4096
#define DMODEL 1024
#define MROWS 8192   // B*N

__device__ __forceinline__ unsigned short f2bf(float f) {
  union { float f; unsigned u; } v; v.f = f;
  unsigned r = v.u + 0x7fffu + ((v.u >> 16) & 1u);
  return (unsigned short)(r >> 16);
}

// packed RNE bf16x2 via the HW instruction (identical rounding to f2bf; 1 instr vs ~10)
__device__ __forceinline__ unsigned pkc(float lo, float hi) {
  unsigned r;
  asm("v_cvt_pk_bf16_f32 %0, %1, %2" : "=v"(r) : "v"(lo), "v"(hi));
  return r;
}

__device__ __forceinline__ void gload16(const unsigned short* g, unsigned short* l) {
  __builtin_amdgcn_global_load_lds(
      (const __attribute__((address_space(1))) unsigned int*)g,
      (__attribute__((address_space(3))) unsigned int*)l, 16, 0, 0);
}

// 4-lane-group (stride-16) transpose step: from (x, y) produce the two B-operand words.
__device__ __forceinline__ void pexch(unsigned x, unsigned y, unsigned& w_lo, unsigned& w_hi) {
  uint32x2 t = __builtin_amdgcn_permlane32_swap(x, y, false, false);
  uint32x2 u = __builtin_amdgcn_permlane16_swap(t[0], t[1], false, false);
  w_lo = u[0];
  w_hi = u[1];
}

// ---------------- fp32 -> bf16 convert (vectorized) ----------------
__global__ void k_conv(const float* __restrict__ src, unsigned short* __restrict__ dst) {
  int i = (blockIdx.x * 256 + threadIdx.x) * 4;
  float4 v = *(const float4*)(src + i);
  ushort4 o;
  o.x = f2bf(v.x); o.y = f2bf(v.y); o.z = f2bf(v.z); o.w = f2bf(v.w);
  *(ushort4*)(dst + i) = o;
}

// ---------------- 4 weight converts in one dispatch; Wq gets log2e/8 folded in ----------------
__global__ void k_convw(const float* __restrict__ s0, const float* __restrict__ s1,
                        const float* __restrict__ s2, const float* __restrict__ s3,
                        unsigned short* __restrict__ dst) {
  int z = blockIdx.x >> 10;
  const float* src = (z == 0) ? s0 : (z == 1) ? s1 : (z == 2) ? s2 : s3;
  float sc = (z == 0) ? 0.18033688011112042f : 1.0f;   // (1/8)*log2(e) folded into Wq
  int i = ((blockIdx.x & 1023) * 256 + threadIdx.x) * 4;
  float4 v = *(const float4*)(src + i);
  ushort4 o;
  o.x = f2bf(v.x * sc); o.y = f2bf(v.y * sc); o.z = f2bf(v.z * sc); o.w = f2bf(v.w * sc);
  *(ushort4*)(dst + (size_t)z * 1048576 + i) = o;
}

// ---------------- RoPE tables (f32): cos/sin[pos][j], j=0..31 ----------------
__global__ void k_rope_tab(float* __restrict__ cosT, float* __restrict__ sinT) {
  int i = blockIdx.x * 256 + threadIdx.x;   // 0..131071
  int pos = i >> 5, j = i & 31;
  float invf = exp2f(-(float)j * 0.41524101186092029f);  // 10000^(-j/32)
  float ang = (float)pos * invf;
  cosT[i] = cosf(ang);
  sinT[i] = sinf(ang);
}

// ---------------- GEMM  C[M,N] = A[M,K] * B[N,K]^T  (bf16 in, mode-dependent epilogue)
// 1D grid, XCD-chunked bijective swizzle. mode: -1 => z-slice decode (0=Q rope, 1=K rope,
// 2=V -> transposed Vt store), 3 => fp32 store (LDS-transposed, coalesced float4).
__global__ __launch_bounds__(256) void k_gemm_bt(
    const unsigned short* __restrict__ A,
    const unsigned short* __restrict__ Bw,
    unsigned short* __restrict__ obf,
    unsigned short* __restrict__ Vt,
    float* __restrict__ of32,
    const float* __restrict__ cosT, const float* __restrict__ sinT,
    int K, int modeArg) {
  const int N = DMODEL;
  const int q8 = gridDim.x >> 3;
  const int wg = (blockIdx.x & 7) * q8 + (blockIdx.x >> 3);
  const int z = wg >> 9;            // 512 wgs per z-slice (8 bn x 64 bm)
  const int rr = wg & 511;
  const int bn = rr & 7, bm = rr >> 3;
  const int mode = (modeArg < 0) ? z : modeArg;
  const unsigned short* Bz = Bw + (size_t)z * DMODEL * K;
  unsigned short* oz = (obf && mode <= 1) ? (obf + (size_t)z * MROWS * DMODEL) : nullptr;

  const int t = threadIdx.x;
  const int w = t >> 6, lane = t & 63;
  const int wr = w >> 1, wc = w & 1;
  const int lr = lane & 15, lg = lane >> 4;

  __shared__ __align__(16) unsigned short SM[2][128 * 64];
  unsigned short* Al = SM[0];
  unsigned short* Bl = SM[1];

  const unsigned short* Ab = A + (size_t)bm * 128 * K;
  const unsigned short* Bb = Bz + (size_t)bn * 128 * K;
  const int trow = t >> 3, tcol = (t & 7) * 8;

  f32x4 acc[4][4] = {};

  for (int k0 = 0; k0 < K; k0 += 64) {
#pragma unroll
    for (int c = 0; c < 4; ++c) {
      gload16(Ab + (size_t)(c * 32 + trow) * K + k0 + tcol, &Al[c * 2048 + t * 8]);
      gload16(Bb + (size_t)(c * 32 + trow) * K + k0 + tcol, &Bl[c * 2048 + t * 8]);
    }
    asm volatile("s_waitcnt vmcnt(0)" ::: "memory");
    __syncthreads();
#pragma unroll
    for (int kk = 0; kk < 2; ++kk) {
      short8 af[4], bfr[4];
#pragma unroll
      for (int mi = 0; mi < 4; ++mi)
        af[mi] = *(const short8*)&Al[(wr * 64 + mi * 16 + lr) * 64 + kk * 32 + lg * 8];
#pragma unroll
      for (int ni = 0; ni < 4; ++ni)
        bfr[ni] = *(const short8*)&Bl[(wc * 64 + ni * 16 + lr) * 64 + kk * 32 + lg * 8];
#pragma unroll
      for (int mi = 0; mi < 4; ++mi)
#pragma unroll
        for (int ni = 0; ni < 4; ++ni)
          acc[mi][ni] = __builtin_amdgcn_mfma_f32_16x16x32_bf16(af[mi], bfr[ni], acc[mi][ni], 0, 0, 0);
    }
    __syncthreads();
  }

  if (mode <= 1 || mode == 3) {
    // ---- C -> LDS transpose (2 half-tiles of 64 rows), coalesced row output ----
    float* Cf = (float*)&SM[0][0];   // 64 x 128 fp32 = 32 KB (exactly Al+Bl)
#pragma unroll
    for (int half = 0; half < 2; ++half) {
      if (half) __syncthreads();
      if (wr == half) {
#pragma unroll
        for (int mi = 0; mi < 4; ++mi)
#pragma unroll
          for (int ni = 0; ni < 4; ++ni)
#pragma unroll
            for (int r = 0; r < 4; ++r) {
              int row = mi * 16 + lg * 4 + r;
              int col = (wc * 64 + ni * 16 + lr) ^ (lg << 3);   // XOR keeps writes 2-way (free)
              Cf[row * 128 + col] = acc[mi][ni][r];
            }
      }
      __syncthreads();
      int pr = t >> 2;
      int gm = bm * 128 + half * 64 + pr;
      int xorv = ((pr >> 2) & 3) << 3;
      if (mode == 3) {
        float* orow = of32 + (size_t)gm * N + bn * 128;
#pragma unroll
        for (int k = 0; k < 4; ++k) {
          int c0 = (t & 3) * 8 + k * 32;
          int cs = c0 ^ xorv;
          float4 va = *(const float4*)&Cf[pr * 128 + cs];
          float4 vb = *(const float4*)&Cf[pr * 128 + cs + 4];
          *(float4*)(orow + c0) = va;
          *(float4*)(orow + c0 + 4) = vb;
        }
      } else {
        int pos = gm & (NSEQ - 1);
        const float* cB = cosT + pos * 32;
        const float* sB = sinT + pos * 32;
        unsigned short* orow = oz + (size_t)gm * N + bn * 128;
#pragma unroll
        for (int k = 0; k < 4; ++k) {
          int c0 = (t & 3) * 8 + k * 32;          // logical col (8 cols = 4 rope pairs)
          int cs = c0 ^ xorv;
          float4 va = *(const float4*)&Cf[pr * 128 + cs];
          float4 vb = *(const float4*)&Cf[pr * 128 + cs + 4];
          int j0 = (c0 & 63) >> 1;
          float4 cv = *(const float4*)&cB[j0];
          float4 sv = *(const float4*)&sB[j0];
          uint4 o;
          o.x = pkc(va.x * cv.x - va.y * sv.x, va.x * sv.x + va.y * cv.x);
          o.y = pkc(va.z * cv.y - va.w * sv.y, va.z * sv.y + va.w * cv.y);
          o.z = pkc(vb.x * cv.z - vb.y * sv.z, vb.x * sv.z + vb.y * cv.z);
          o.w = pkc(vb.z * cv.w - vb.w * sv.w, vb.z * sv.w + vb.w * cv.w);
          *(uint4*)(orow + c0) = o;
        }
      }
    }
  } else {
    // mode 2: fused V^T store: lane's 4 regs are 4 consecutive n at fixed channel gn
#pragma unroll
    for (int mi = 0; mi < 4; ++mi)
#pragma unroll
      for (int ni = 0; ni < 4; ++ni) {
        int gm0 = bm * 128 + wr * 64 + mi * 16 + lg * 4;
        int gn = bn * 128 + wc * 64 + ni * 16 + lr;
        int b = gm0 >> 12, n = gm0 & (NSEQ - 1);
        int h = gn >> 6, d = gn & 63;
        uint2 u;
        u.x = pkc(acc[mi][ni][0], acc[mi][ni][1]);
        u.y = pkc(acc[mi][ni][2], acc[mi][ni][3]);
        *(uint2*)(Vt + ((size_t)((b * 16 + h) * 64 + d)) * NSEQ + n) = u;
      }
  }
}

// ---------------- causal flash attention, swapped-operand (S^T / O^T), fixed-max ----------------
// R18 = R16 + T4 counted-vmcnt pipeline, triple-buffered K/V (prefetch distance 2).
// Step t: read frags from buf[t%3] FIRST, then restage tile t+3 into buf[t%3] (writes can't
// land before issue; reads precede issue -> no race), compute, then s_waitcnt vmcnt(8)
// (tiles t+1,t+2 = 8 newest ops stay in flight; t+1 guaranteed drained) + raw s_barrier.
// Old structure drained next-tile HBM loads at every barrier (4 bh x 2MB K/V = 8MB > 4MB
// L2/XCD -> frequent ~900cy misses). qi-boundary fully drains (no restage write-write race).
// Grid 512 uniform pairs (qt = 31-pq then pq), 4 waves x 32 q, in-register P relayout
// (permlane), cvt_pk packing. LDS = 3x8K(K)+3x8K(V)+8K(Pl) = 56KB -> 2 blocks/CU.
// Softmax: P = exp2(S), no max subtraction. l via ones-A MFMA.
__global__ __launch_bounds__(256, 2) void k_attn14(
    const unsigned short* __restrict__ Qb,
    const unsigned short* __restrict__ Kb,
    const unsigned short* __restrict__ Vtg,
    unsigned short* __restrict__ AO) {
  const int id = blockIdx.x;
  const int bh = id & 31;
  const int pq = id >> 5;            // 0..15
  const int b = bh >> 4, h = bh & 15;
  const int t = threadIdx.x;
  const int w = t >> 6, lane = t & 63;
  const int lr = lane & 15, hi4 = lane >> 4;
  const size_t rowbase = (size_t)b * NSEQ;

  __shared__ __align__(16) unsigned short Kl[3][64 * 64];
  __shared__ __align__(16) unsigned short Vl[3][64 * 64];
  __shared__ __align__(16) unsigned short Pl[4][16 * 64];   // epilogue-only

  const int pswz = (lr & 7) << 3;

  short8 ones;
#pragma unroll
  for (int i = 0; i < 8; ++i) ones[i] = (short)0x3F80;   // bf16 1.0

#define STAGE(buf, kv0)                                                                   \
  {                                                                                       \
    _Pragma("unroll")                                                                     \
    for (int it = 0; it < 2; ++it) {                                                      \
      int c = t + it * 256;                                                               \
      int row = c >> 3, sg = (c & 7) ^ (row & 7);                                         \
      gload16(Kb + (rowbase + (kv0) + row) * DMODEL + h * 64 + sg * 8, &Kl[buf][c * 8]);  \
      gload16(Vtg + ((size_t)bh * 64 + row) * NSEQ + (kv0) + sg * 8, &Vl[buf][c * 8]);    \
    }                                                                                     \
  }

#pragma unroll
  for (int qi = 0; qi < 2; ++qi) {
    const int qt = qi ? pq : (31 - pq);
    const int q0w = qt * 128 + w * 32;

    short8 qf[2][2];
#pragma unroll
    for (int sub = 0; sub < 2; ++sub) {
      const unsigned short* qp = Qb + (rowbase + q0w + sub * 16 + lr) * DMODEL + h * 64 + hi4 * 8;
#pragma unroll
      for (int s = 0; s < 2; ++s)
        qf[sub][s] = *(const short8*)(qp + s * 32);
    }

    f32x4 oacc[2][4] = {};
    f32x4 lacc[2] = {};
    const int nkv = (qt + 1) * 2;
    const int kvlast = (nkv - 1) * 64;

    // prologue: prime 3 tiles; vmcnt(8) retires Q loads + tile 0 (8 newest = tiles 1,2)
    STAGE(0, 0);
    STAGE(1, (64 < kvlast ? 64 : kvlast));
    STAGE(2, (128 < kvlast ? 128 : kvlast));
    asm volatile("s_waitcnt vmcnt(8)" ::: "memory");
    __builtin_amdgcn_s_barrier();

    int cur = 0;
    for (int ib = 0; ib < nkv; ++ib) {
      const int kv0 = ib * 64;
      const bool live = (kv0 <= q0w + 31);

      // 1) read all frags of buffer cur BEFORE reusing it for the restage
      short8 Kf[4][2], Vf[2][4];
      if (live) {
#pragma unroll
        for (int t4 = 0; t4 < 4; ++t4)
#pragma unroll
          for (int s = 0; s < 2; ++s)
            Kf[t4][s] = *(const short8*)&Kl[cur][(t4 * 16 + lr) * 64 + (((s * 4 + hi4) ^ (lr & 7)) * 8)];
#pragma unroll
        for (int c = 0; c < 2; ++c)
#pragma unroll
          for (int dt = 0; dt < 4; ++dt)
            Vf[c][dt] = *(const short8*)&Vl[cur][(dt * 16 + lr) * 64 + (((c * 4 + hi4) ^ (lr & 7)) * 8)];
        // frag reads must complete before the restage below overwrites buf[cur]
        asm volatile("s_waitcnt lgkmcnt(0)" ::: "memory");
        __builtin_amdgcn_sched_barrier(0);
      }
      // all waves' frag reads of buf[cur] done before ANY wave's restage lands:
      __builtin_amdgcn_s_barrier();

      // 2) restage tile ib+3 into buf[cur] (distance-2 ring)
      {
        int kvn = kv0 + 192;
        if (kvn > kvlast) kvn = kvlast;
        STAGE(cur, kvn);
      }

      // 3) compute tile ib from registers
      if (live) {
#pragma unroll
        for (int sub = 0; sub < 2; ++sub) {
          const int qs = q0w + sub * 16;
          const int qlane = qs + lr;
          f32x4 sa[4];
          const f32x4 zz = {0.f, 0.f, 0.f, 0.f};
          __builtin_amdgcn_s_setprio(1);
#pragma unroll
          for (int t4 = 0; t4 < 4; ++t4) {
            f32x4 x = __builtin_amdgcn_mfma_f32_16x16x32_bf16(Kf[t4][0], qf[sub][0], zz, 0, 0, 0);
            sa[t4] = __builtin_amdgcn_mfma_f32_16x16x32_bf16(Kf[t4][1], qf[sub][1], x, 0, 0, 0);
          }
          __builtin_amdgcn_s_setprio(0);
          if (kv0 + 63 > qs) {
#pragma unroll
            for (int t4 = 0; t4 < 4; ++t4)
#pragma unroll
              for (int r = 0; r < 4; ++r)
                if (kv0 + t4 * 16 + hi4 * 4 + r > qlane) sa[t4][r] = -1e30f;
          }
#pragma unroll
          for (int t4 = 0; t4 < 4; ++t4)
#pragma unroll
            for (int r = 0; r < 4; ++r)
              sa[t4][r] = __builtin_amdgcn_exp2f(sa[t4][r]);

          unsigned a0 = pkc(sa[0][0], sa[0][1]), a1 = pkc(sa[0][2], sa[0][3]);
          unsigned a2 = pkc(sa[1][0], sa[1][1]), a3 = pkc(sa[1][2], sa[1][3]);
          unsigned a4 = pkc(sa[2][0], sa[2][1]), a5 = pkc(sa[2][2], sa[2][3]);
          unsigned a6 = pkc(sa[3][0], sa[3][1]), a7 = pkc(sa[3][2], sa[3][3]);
          unsigned w0, w1, w2, w3, x0, x1, x2, x3;
          pexch(a0, a2, w0, w2);
          pexch(a1, a3, w1, w3);
          pexch(a4, a6, x0, x2);
          pexch(a5, a7, x1, x3);
          union { uint4 u; short8 s; } P0, P1;
          P0.u.x = w0; P0.u.y = w1; P0.u.z = w2; P0.u.w = w3;
          P1.u.x = x0; P1.u.y = x1; P1.u.z = x2; P1.u.w = x3;
          short8 pf0 = P0.s;
          short8 pf1 = P1.s;

          __builtin_amdgcn_s_setprio(1);
#pragma unroll
          for (int dt = 0; dt < 4; ++dt) {
            oacc[sub][dt] = __builtin_amdgcn_mfma_f32_16x16x32_bf16(Vf[0][dt], pf0, oacc[sub][dt], 0, 0, 0);
            oacc[sub][dt] = __builtin_amdgcn_mfma_f32_16x16x32_bf16(Vf[1][dt], pf1, oacc[sub][dt], 0, 0, 0);
          }
          lacc[sub] = __builtin_amdgcn_mfma_f32_16x16x32_bf16(ones, pf0, lacc[sub], 0, 0, 0);
          lacc[sub] = __builtin_amdgcn_mfma_f32_16x16x32_bf16(ones, pf1, lacc[sub], 0, 0, 0);
          __builtin_amdgcn_s_setprio(0);
        }
      }

      // 4) tiles t+2,t+3 (8 newest ops) may stay in flight; tile t+1 guaranteed drained
      asm volatile("s_waitcnt vmcnt(8)" ::: "memory");
      __builtin_amdgcn_s_barrier();
      cur = (cur == 2) ? 0 : cur + 1;
    }

    // qi boundary / pre-epilogue: full drain so next restage can't race leftover writes
    asm volatile("s_waitcnt vmcnt(0)" ::: "memory");
    __builtin_amdgcn_s_barrier();

    // epilogue: O^T/l -> per-wave LDS transpose (swizzled) -> coalesced bf16 stores
#pragma unroll
    for (int sub = 0; sub < 2; ++sub) {
      float inv = 1.f / lacc[sub][0];
#pragma unroll
      for (int dt = 0; dt < 4; ++dt) {
        uint2 u;
        u.x = pkc(oacc[sub][dt][0] * inv, oacc[sub][dt][1] * inv);
        u.y = pkc(oacc[sub][dt][2] * inv, oacc[sub][dt][3] * inv);
        *(uint2*)&Pl[w][lr * 64 + ((dt * 16 + hi4 * 4) ^ pswz)] = u;
      }
      asm volatile("s_waitcnt lgkmcnt(0)" ::: "memory");
      __builtin_amdgcn_sched_barrier(0);
      int q2 = lane >> 2, ch = (lane & 3) * 16;
      int qswz = (q2 & 7) << 3;
      uint4 r0 = *(const uint4*)&Pl[w][q2 * 64 + (ch ^ qswz)];
      uint4 r1 = *(const uint4*)&Pl[w][q2 * 64 + ((ch + 8) ^ qswz)];
      unsigned short* op = AO + (rowbase + q0w + sub * 16 + q2) * DMODEL + h * 64 + ch;
      *(uint4*)op = r0;
      *(uint4*)(op + 8) = r1;
      asm volatile("s_waitcnt lgkmcnt(0)" ::: "memory");
      __builtin_amdgcn_sched_barrier(0);
    }
  }
}

extern "C" void kernel_launch(void* const* d_in, const int* in_sizes, int n_in,
                              void* d_out, int out_size, void* d_ws, size_t ws_size,
                              hipStream_t stream) {
  const float* x  = (const float*)d_in[0];
  const float* Wq = (const float*)d_in[1];
  const float* Wk = (const float*)d_in[2];
  const float* Wv = (const float*)d_in[3];
  const float* Wo = (const float*)d_in[4];
  float* out = (float*)d_out;
  char* ws = (char*)d_ws;

  // ws layout (bytes):
  unsigned short* xb  = (unsigned short*)(ws);                 // 16 MB
  unsigned short* Wb  = (unsigned short*)(ws + 16777216);      // 4 x 2 MB (q,k,v,o)
  unsigned short* Qb  = (unsigned short*)(ws + 25165824);      // 16 MB
  unsigned short* Kb  = Qb + 8388608;                          // 16 MB @ 41943040
  unsigned short* Vtg = (unsigned short*)(ws + 58720256);      // 16 MB (V^T [bh*64+d][n])
  unsigned short* AO  = (unsigned short*)(ws + 75497472);      // 16 MB
  float* cosT = (float*)(ws + 92274688);                       // 512 KB
  float* sinT = (float*)(ws + 92798976);                       // 512 KB

  k_conv<<<8192, 256, 0, stream>>>(x, xb);
  k_convw<<<4096, 256, 0, stream>>>(Wq, Wk, Wv, Wo, Wb);
  k_rope_tab<<<512, 256, 0, stream>>>(cosT, sinT);

  // fused Q/K/V projections (+RoPE; scale folded into Wq), bf16 out; V stored transposed to Vtg
  k_gemm_bt<<<1536, 256, 0, stream>>>(xb, Wb, Qb, Vtg, nullptr, cosT, sinT, DMODEL, -1);

  // causal flash attention (counted-vmcnt triple-buffer pipeline)
  k_attn14<<<512, 256, 0, stream>>>(Qb, Kb, Vtg, AO);

  // output projection, fp32 out
  k_gemm_bt<<<512, 256, 0, stream>>>(AO, Wb + 3145728, nullptr, nullptr, out, cosT, sinT, DMODEL, 3);
}

// Round 19
// 217.108 us; speedup vs baseline: 1.0139x; 1.0131x over previous
//
#include <hip/hip_runtime.h>
#include <hip/hip_bf16.h>
#include <stdint.h>

typedef __attribute__((ext_vector_type(8))) short short8;
typedef __attribute__((ext_vector_type(4))) float f32x4;
typedef __attribute__((ext_vector_type(2))) unsigned uint32x2;

#define NSEQ 4096
#define DMODEL 1024
#define MROWS 8192   // B*N

__device__ __forceinline__ unsigned short f2bf(float f) {
  union { float f; unsigned u; } v; v.f = f;
  unsigned r = v.u + 0x7fffu + ((v.u >> 16) & 1u);
  return (unsigned short)(r >> 16);
}

// packed RNE bf16x2 via the HW instruction (identical rounding to f2bf; 1 instr vs ~10)
__device__ __forceinline__ unsigned pkc(float lo, float hi) {
  unsigned r;
  asm("v_cvt_pk_bf16_f32 %0, %1, %2" : "=v"(r) : "v"(lo), "v"(hi));
  return r;
}

__device__ __forceinline__ void gload16(const unsigned short* g, unsigned short* l) {
  __builtin_amdgcn_global_load_lds(
      (const __attribute__((address_space(1))) unsigned int*)g,
      (__attribute__((address_space(3))) unsigned int*)l, 16, 0, 0);
}

// 4-lane-group (stride-16) transpose step: from (x, y) produce the two B-operand words.
__device__ __forceinline__ void pexch(unsigned x, unsigned y, unsigned& w_lo, unsigned& w_hi) {
  uint32x2 t = __builtin_amdgcn_permlane32_swap(x, y, false, false);
  uint32x2 u = __builtin_amdgcn_permlane16_swap(t[0], t[1], false, false);
  w_lo = u[0];
  w_hi = u[1];
}

// ---------------- fused prep: x convert (bids 0..8191), weight converts (8192..12287,
// Wq scaled by log2e/8), RoPE tables (12288..12799) ----------------
__global__ void k_prep(const float* __restrict__ x,
                       const float* __restrict__ Wq, const float* __restrict__ Wk,
                       const float* __restrict__ Wv, const float* __restrict__ Wo,
                       unsigned short* __restrict__ xb, unsigned short* __restrict__ Wb,
                       float* __restrict__ cosT, float* __restrict__ sinT) {
  int bid = blockIdx.x;
  if (bid < 8192) {
    int i = (bid * 256 + threadIdx.x) * 4;
    float4 v = *(const float4*)(x + i);
    ushort4 o;
    o.x = f2bf(v.x); o.y = f2bf(v.y); o.z = f2bf(v.z); o.w = f2bf(v.w);
    *(ushort4*)(xb + i) = o;
  } else if (bid < 12288) {
    int r = bid - 8192;
    int z = r >> 10;
    const float* src = (z == 0) ? Wq : (z == 1) ? Wk : (z == 2) ? Wv : Wo;
    float sc = (z == 0) ? 0.18033688011112042f : 1.0f;   // (1/8)*log2(e) folded into Wq
    int i = ((r & 1023) * 256 + threadIdx.x) * 4;
    float4 v = *(const float4*)(src + i);
    ushort4 o;
    o.x = f2bf(v.x * sc); o.y = f2bf(v.y * sc); o.z = f2bf(v.z * sc); o.w = f2bf(v.w * sc);
    *(ushort4*)(Wb + (size_t)z * 1048576 + i) = o;
  } else {
    int i = (bid - 12288) * 256 + threadIdx.x;   // 0..131071
    int pos = i >> 5, j = i & 31;
    float invf = exp2f(-(float)j * 0.41524101186092029f);  // 10000^(-j/32)
    float ang = (float)pos * invf;
    cosT[i] = cosf(ang);
    sinT[i] = sinf(ang);
  }
}

// ---------------- GEMM  C[M,N] = A[M,K] * B[N,K]^T  (bf16 in, mode-dependent epilogue)
// 1D grid, XCD-chunked bijective swizzle. mode: -1 => z-slice decode (0=Q rope, 1=K rope,
// 2=V -> transposed Vt store), 3 => fp32 store (LDS-transposed, coalesced float4).
__global__ __launch_bounds__(256) void k_gemm_bt(
    const unsigned short* __restrict__ A,
    const unsigned short* __restrict__ Bw,
    unsigned short* __restrict__ obf,
    unsigned short* __restrict__ Vt,
    float* __restrict__ of32,
    const float* __restrict__ cosT, const float* __restrict__ sinT,
    int K, int modeArg) {
  const int N = DMODEL;
  const int q8 = gridDim.x >> 3;
  const int wg = (blockIdx.x & 7) * q8 + (blockIdx.x >> 3);
  const int z = wg >> 9;            // 512 wgs per z-slice (8 bn x 64 bm)
  const int rr = wg & 511;
  const int bn = rr & 7, bm = rr >> 3;
  const int mode = (modeArg < 0) ? z : modeArg;
  const unsigned short* Bz = Bw + (size_t)z * DMODEL * K;
  unsigned short* oz = (obf && mode <= 1) ? (obf + (size_t)z * MROWS * DMODEL) : nullptr;

  const int t = threadIdx.x;
  const int w = t >> 6, lane = t & 63;
  const int wr = w >> 1, wc = w & 1;
  const int lr = lane & 15, lg = lane >> 4;

  __shared__ __align__(16) unsigned short SM[2][128 * 64];
  unsigned short* Al = SM[0];
  unsigned short* Bl = SM[1];

  const unsigned short* Ab = A + (size_t)bm * 128 * K;
  const unsigned short* Bb = Bz + (size_t)bn * 128 * K;
  const int trow = t >> 3, tcol = (t & 7) * 8;

  f32x4 acc[4][4] = {};

  for (int k0 = 0; k0 < K; k0 += 64) {
#pragma unroll
    for (int c = 0; c < 4; ++c) {
      gload16(Ab + (size_t)(c * 32 + trow) * K + k0 + tcol, &Al[c * 2048 + t * 8]);
      gload16(Bb + (size_t)(c * 32 + trow) * K + k0 + tcol, &Bl[c * 2048 + t * 8]);
    }
    asm volatile("s_waitcnt vmcnt(0)" ::: "memory");
    __syncthreads();
#pragma unroll
    for (int kk = 0; kk < 2; ++kk) {
      short8 af[4], bfr[4];
#pragma unroll
      for (int mi = 0; mi < 4; ++mi)
        af[mi] = *(const short8*)&Al[(wr * 64 + mi * 16 + lr) * 64 + kk * 32 + lg * 8];
#pragma unroll
      for (int ni = 0; ni < 4; ++ni)
        bfr[ni] = *(const short8*)&Bl[(wc * 64 + ni * 16 + lr) * 64 + kk * 32 + lg * 8];
#pragma unroll
      for (int mi = 0; mi < 4; ++mi)
#pragma unroll
        for (int ni = 0; ni < 4; ++ni)
          acc[mi][ni] = __builtin_amdgcn_mfma_f32_16x16x32_bf16(af[mi], bfr[ni], acc[mi][ni], 0, 0, 0);
    }
    __syncthreads();
  }

  if (mode <= 1 || mode == 3) {
    // ---- C -> LDS transpose (2 half-tiles of 64 rows), coalesced row output ----
    float* Cf = (float*)&SM[0][0];   // 64 x 128 fp32 = 32 KB (exactly Al+Bl)
#pragma unroll
    for (int half = 0; half < 2; ++half) {
      if (half) __syncthreads();
      if (wr == half) {
#pragma unroll
        for (int mi = 0; mi < 4; ++mi)
#pragma unroll
          for (int ni = 0; ni < 4; ++ni)
#pragma unroll
            for (int r = 0; r < 4; ++r) {
              int row = mi * 16 + lg * 4 + r;
              int col = (wc * 64 + ni * 16 + lr) ^ (lg << 3);   // XOR keeps writes 2-way (free)
              Cf[row * 128 + col] = acc[mi][ni][r];
            }
      }
      __syncthreads();
      int pr = t >> 2;
      int gm = bm * 128 + half * 64 + pr;
      int xorv = ((pr >> 2) & 3) << 3;
      if (mode == 3) {
        float* orow = of32 + (size_t)gm * N + bn * 128;
#pragma unroll
        for (int k = 0; k < 4; ++k) {
          int c0 = (t & 3) * 8 + k * 32;
          int cs = c0 ^ xorv;
          float4 va = *(const float4*)&Cf[pr * 128 + cs];
          float4 vb = *(const float4*)&Cf[pr * 128 + cs + 4];
          *(float4*)(orow + c0) = va;
          *(float4*)(orow + c0 + 4) = vb;
        }
      } else {
        int pos = gm & (NSEQ - 1);
        const float* cB = cosT + pos * 32;
        const float* sB = sinT + pos * 32;
        unsigned short* orow = oz + (size_t)gm * N + bn * 128;
#pragma unroll
        for (int k = 0; k < 4; ++k) {
          int c0 = (t & 3) * 8 + k * 32;          // logical col (8 cols = 4 rope pairs)
          int cs = c0 ^ xorv;
          float4 va = *(const float4*)&Cf[pr * 128 + cs];
          float4 vb = *(const float4*)&Cf[pr * 128 + cs + 4];
          int j0 = (c0 & 63) >> 1;
          float4 cv = *(const float4*)&cB[j0];
          float4 sv = *(const float4*)&sB[j0];
          uint4 o;
          o.x = pkc(va.x * cv.x - va.y * sv.x, va.x * sv.x + va.y * cv.x);
          o.y = pkc(va.z * cv.y - va.w * sv.y, va.z * sv.y + va.w * cv.y);
          o.z = pkc(vb.x * cv.z - vb.y * sv.z, vb.x * sv.z + vb.y * cv.z);
          o.w = pkc(vb.z * cv.w - vb.w * sv.w, vb.z * sv.w + vb.w * cv.w);
          *(uint4*)(orow + c0) = o;
        }
      }
    }
  } else {
    // mode 2: fused V^T store: lane's 4 regs are 4 consecutive n at fixed channel gn
#pragma unroll
    for (int mi = 0; mi < 4; ++mi)
#pragma unroll
      for (int ni = 0; ni < 4; ++ni) {
        int gm0 = bm * 128 + wr * 64 + mi * 16 + lg * 4;
        int gn = bn * 128 + wc * 64 + ni * 16 + lr;
        int b = gm0 >> 12, n = gm0 & (NSEQ - 1);
        int h = gn >> 6, d = gn & 63;
        uint2 u;
        u.x = pkc(acc[mi][ni][0], acc[mi][ni][1]);
        u.y = pkc(acc[mi][ni][2], acc[mi][ni][3]);
        *(uint2*)(Vt + ((size_t)((b * 16 + h) * 64 + d)) * NSEQ + n) = u;
      }
  }
}

// ---------------- causal flash attention, swapped-operand (S^T / O^T), fixed-max ----------------
// R19 = R16's k_attn12 verbatim (best measured: 98.2 us; R17 static-unroll +0.4, R18
// counted-vmcnt +1.0 — this structure's floor). Grid 512 uniform pairs (qt = 31-pq then pq),
// 4 waves x 32 q, KVBLK=64 double-buffered, in-register P relayout (permlane32/16_swap),
// v_cvt_pk_bf16_f32 packing, P = exp2(S) fixed-max softmax, l via ones-A MFMA.
__global__ __launch_bounds__(256, 2) void k_attn12(
    const unsigned short* __restrict__ Qb,
    const unsigned short* __restrict__ Kb,
    const unsigned short* __restrict__ Vtg,
    unsigned short* __restrict__ AO) {
  const int id = blockIdx.x;
  const int bh = id & 31;
  const int pq = id >> 5;            // 0..15
  const int b = bh >> 4, h = bh & 15;
  const int t = threadIdx.x;
  const int w = t >> 6, lane = t & 63;
  const int lr = lane & 15, hi4 = lane >> 4;
  const size_t rowbase = (size_t)b * NSEQ;

  __shared__ __align__(16) unsigned short Kl[2][64 * 64];
  __shared__ __align__(16) unsigned short Vl[2][64 * 64];
  __shared__ __align__(16) unsigned short Pl[4][16 * 64];   // epilogue-only

  const int pswz = (lr & 7) << 3;

  short8 ones;
#pragma unroll
  for (int i = 0; i < 8; ++i) ones[i] = (short)0x3F80;   // bf16 1.0

#define STAGE(buf, kv0)                                                                   \
  {                                                                                       \
    _Pragma("unroll")                                                                     \
    for (int it = 0; it < 2; ++it) {                                                      \
      int c = t + it * 256;                                                               \
      int row = c >> 3, sg = (c & 7) ^ (row & 7);                                         \
      gload16(Kb + (rowbase + (kv0) + row) * DMODEL + h * 64 + sg * 8, &Kl[buf][c * 8]);  \
      gload16(Vtg + ((size_t)bh * 64 + row) * NSEQ + (kv0) + sg * 8, &Vl[buf][c * 8]);    \
    }                                                                                     \
  }

#pragma unroll
  for (int qi = 0; qi < 2; ++qi) {
    const int qt = qi ? pq : (31 - pq);
    const int q0w = qt * 128 + w * 32;

    short8 qf[2][2];
#pragma unroll
    for (int sub = 0; sub < 2; ++sub) {
      const unsigned short* qp = Qb + (rowbase + q0w + sub * 16 + lr) * DMODEL + h * 64 + hi4 * 8;
#pragma unroll
      for (int s = 0; s < 2; ++s)
        qf[sub][s] = *(const short8*)(qp + s * 32);
    }

    f32x4 oacc[2][4] = {};
    f32x4 lacc[2] = {};
    const int nkv = (qt + 1) * 2;

    STAGE(0, 0);
    asm volatile("s_waitcnt vmcnt(0)" ::: "memory");
    __syncthreads();

    for (int ib = 0; ib < nkv; ++ib) {
      const int kv0 = ib * 64, cur = ib & 1;
      if (ib + 1 < nkv) STAGE(cur ^ 1, kv0 + 64);

      if (kv0 <= q0w + 31) {
        short8 Kf[4][2], Vf[2][4];
#pragma unroll
        for (int t4 = 0; t4 < 4; ++t4)
#pragma unroll
          for (int s = 0; s < 2; ++s)
            Kf[t4][s] = *(const short8*)&Kl[cur][(t4 * 16 + lr) * 64 + (((s * 4 + hi4) ^ (lr & 7)) * 8)];
#pragma unroll
        for (int c = 0; c < 2; ++c)
#pragma unroll
          for (int dt = 0; dt < 4; ++dt)
            Vf[c][dt] = *(const short8*)&Vl[cur][(dt * 16 + lr) * 64 + (((c * 4 + hi4) ^ (lr & 7)) * 8)];

#pragma unroll
        for (int sub = 0; sub < 2; ++sub) {
          const int qs = q0w + sub * 16;
          const int qlane = qs + lr;
          f32x4 sa[4];
          const f32x4 zz = {0.f, 0.f, 0.f, 0.f};
          __builtin_amdgcn_s_setprio(1);
#pragma unroll
          for (int t4 = 0; t4 < 4; ++t4) {
            f32x4 x = __builtin_amdgcn_mfma_f32_16x16x32_bf16(Kf[t4][0], qf[sub][0], zz, 0, 0, 0);
            sa[t4] = __builtin_amdgcn_mfma_f32_16x16x32_bf16(Kf[t4][1], qf[sub][1], x, 0, 0, 0);
          }
          __builtin_amdgcn_s_setprio(0);
          if (kv0 + 63 > qs) {
#pragma unroll
            for (int t4 = 0; t4 < 4; ++t4)
#pragma unroll
              for (int r = 0; r < 4; ++r)
                if (kv0 + t4 * 16 + hi4 * 4 + r > qlane) sa[t4][r] = -1e30f;
          }
#pragma unroll
          for (int t4 = 0; t4 < 4; ++t4)
#pragma unroll
            for (int r = 0; r < 4; ++r)
              sa[t4][r] = __builtin_amdgcn_exp2f(sa[t4][r]);

          // pack via HW cvt_pk: a_{2t4} = P[kv=16t4+4hi4+{0,1}], a_{2t4+1} = +{2,3}
          unsigned a0 = pkc(sa[0][0], sa[0][1]), a1 = pkc(sa[0][2], sa[0][3]);
          unsigned a2 = pkc(sa[1][0], sa[1][1]), a3 = pkc(sa[1][2], sa[1][3]);
          unsigned a4 = pkc(sa[2][0], sa[2][1]), a5 = pkc(sa[2][2], sa[2][3]);
          unsigned a6 = pkc(sa[3][0], sa[3][1]), a7 = pkc(sa[3][2], sa[3][3]);
          // in-register 4-lane-group transpose -> B-operand words
          unsigned w0, w1, w2, w3, x0, x1, x2, x3;
          pexch(a0, a2, w0, w2);
          pexch(a1, a3, w1, w3);
          pexch(a4, a6, x0, x2);
          pexch(a5, a7, x1, x3);
          union { uint4 u; short8 s; } P0, P1;
          P0.u.x = w0; P0.u.y = w1; P0.u.z = w2; P0.u.w = w3;
          P1.u.x = x0; P1.u.y = x1; P1.u.z = x2; P1.u.w = x3;
          short8 pf0 = P0.s;
          short8 pf1 = P1.s;

          __builtin_amdgcn_s_setprio(1);
#pragma unroll
          for (int dt = 0; dt < 4; ++dt) {
            oacc[sub][dt] = __builtin_amdgcn_mfma_f32_16x16x32_bf16(Vf[0][dt], pf0, oacc[sub][dt], 0, 0, 0);
            oacc[sub][dt] = __builtin_amdgcn_mfma_f32_16x16x32_bf16(Vf[1][dt], pf1, oacc[sub][dt], 0, 0, 0);
          }
          lacc[sub] = __builtin_amdgcn_mfma_f32_16x16x32_bf16(ones, pf0, lacc[sub], 0, 0, 0);
          lacc[sub] = __builtin_amdgcn_mfma_f32_16x16x32_bf16(ones, pf1, lacc[sub], 0, 0, 0);
          __builtin_amdgcn_s_setprio(0);
        }
      }
      asm volatile("s_waitcnt vmcnt(0)" ::: "memory");
      __syncthreads();
    }

    // epilogue: O^T/l -> LDS transpose (swizzled) -> coalesced bf16 stores
#pragma unroll
    for (int sub = 0; sub < 2; ++sub) {
      float inv = 1.f / lacc[sub][0];
#pragma unroll
      for (int dt = 0; dt < 4; ++dt) {
        uint2 u;
        u.x = pkc(oacc[sub][dt][0] * inv, oacc[sub][dt][1] * inv);
        u.y = pkc(oacc[sub][dt][2] * inv, oacc[sub][dt][3] * inv);
        *(uint2*)&Pl[w][lr * 64 + ((dt * 16 + hi4 * 4) ^ pswz)] = u;
      }
      asm volatile("s_waitcnt lgkmcnt(0)" ::: "memory");
      __builtin_amdgcn_sched_barrier(0);
      int q2 = lane >> 2, ch = (lane & 3) * 16;
      int qswz = (q2 & 7) << 3;
      uint4 r0 = *(const uint4*)&Pl[w][q2 * 64 + (ch ^ qswz)];
      uint4 r1 = *(const uint4*)&Pl[w][q2 * 64 + ((ch + 8) ^ qswz)];
      unsigned short* op = AO + (rowbase + q0w + sub * 16 + q2) * DMODEL + h * 64 + ch;
      *(uint4*)op = r0;
      *(uint4*)(op + 8) = r1;
      __syncthreads();
    }
  }
}

extern "C" void kernel_launch(void* const* d_in, const int* in_sizes, int n_in,
                              void* d_out, int out_size, void* d_ws, size_t ws_size,
                              hipStream_t stream) {
  const float* x  = (const float*)d_in[0];
  const float* Wq = (const float*)d_in[1];
  const float* Wk = (const float*)d_in[2];
  const float* Wv = (const float*)d_in[3];
  const float* Wo = (const float*)d_in[4];
  float* out = (float*)d_out;
  char* ws = (char*)d_ws;

  // ws layout (bytes):
  unsigned short* xb  = (unsigned short*)(ws);                 // 16 MB
  unsigned short* Wb  = (unsigned short*)(ws + 16777216);      // 4 x 2 MB (q,k,v,o)
  unsigned short* Qb  = (unsigned short*)(ws + 25165824);      // 16 MB
  unsigned short* Kb  = Qb + 8388608;                          // 16 MB @ 41943040
  unsigned short* Vtg = (unsigned short*)(ws + 58720256);      // 16 MB (V^T [bh*64+d][n])
  unsigned short* AO  = (unsigned short*)(ws + 75497472);      // 16 MB
  float* cosT = (float*)(ws + 92274688);                       // 512 KB
  float* sinT = (float*)(ws + 92798976);                       // 512 KB

  // fused prep: x/weight converts + RoPE tables in one dispatch
  k_prep<<<12800, 256, 0, stream>>>(x, Wq, Wk, Wv, Wo, xb, Wb, cosT, sinT);

  // fused Q/K/V projections (+RoPE; scale folded into Wq), bf16 out; V stored transposed to Vtg
  k_gemm_bt<<<1536, 256, 0, stream>>>(xb, Wb, Qb, Vtg, nullptr, cosT, sinT, DMODEL, -1);

  // causal flash attention (uniform pairs, in-register P exchange, cvt_pk packing)
  k_attn12<<<512, 256, 0, stream>>>(Qb, Kb, Vtg, AO);

  // output projection, fp32 out
  k_gemm_bt<<<512, 256, 0, stream>>>(AO, Wb + 3145728, nullptr, nullptr, out, cosT, sinT, DMODEL, 3);
}

// Round 20
// 191.063 us; speedup vs baseline: 1.1521x; 1.1363x over previous
//
#include <hip/hip_runtime.h>
#include <hip/hip_bf16.h>
#include <stdint.h>

typedef __attribute__((ext_vector_type(8))) short short8;
typedef __attribute__((ext_vector_type(4))) float f32x4;
typedef __attribute__((ext_vector_type(2))) unsigned uint32x2;

#define NSEQ 4096
#define DMODEL 1024
#define MROWS 8192   // B*N

__device__ __forceinline__ unsigned short f2bf(float f) {
  union { float f; unsigned u; } v; v.f = f;
  unsigned r = v.u + 0x7fffu + ((v.u >> 16) & 1u);
  return (unsigned short)(r >> 16);
}

// packed RNE bf16x2 via the HW instruction (identical rounding to f2bf; 1 instr vs ~10)
__device__ __forceinline__ unsigned pkc(float lo, float hi) {
  unsigned r;
  asm("v_cvt_pk_bf16_f32 %0, %1, %2" : "=v"(r) : "v"(lo), "v"(hi));
  return r;
}

__device__ __forceinline__ void gload16(const unsigned short* g, unsigned short* l) {
  __builtin_amdgcn_global_load_lds(
      (const __attribute__((address_space(1))) unsigned int*)g,
      (__attribute__((address_space(3))) unsigned int*)l, 16, 0, 0);
}

// 4-lane-group (stride-16) transpose step: from (x, y) produce the two B-operand words.
__device__ __forceinline__ void pexch(unsigned x, unsigned y, unsigned& w_lo, unsigned& w_hi) {
  uint32x2 t = __builtin_amdgcn_permlane32_swap(x, y, false, false);
  uint32x2 u = __builtin_amdgcn_permlane16_swap(t[0], t[1], false, false);
  w_lo = u[0];
  w_hi = u[1];
}

// ---------------- fused prep: x convert (bids 0..8191), weight converts (8192..12287,
// Wq scaled by log2e/8), RoPE tables (12288..12799) ----------------
__global__ void k_prep(const float* __restrict__ x,
                       const float* __restrict__ Wq, const float* __restrict__ Wk,
                       const float* __restrict__ Wv, const float* __restrict__ Wo,
                       unsigned short* __restrict__ xb, unsigned short* __restrict__ Wb,
                       float* __restrict__ cosT, float* __restrict__ sinT) {
  int bid = blockIdx.x;
  if (bid < 8192) {
    int i = (bid * 256 + threadIdx.x) * 4;
    float4 v = *(const float4*)(x + i);
    ushort4 o;
    o.x = f2bf(v.x); o.y = f2bf(v.y); o.z = f2bf(v.z); o.w = f2bf(v.w);
    *(ushort4*)(xb + i) = o;
  } else if (bid < 12288) {
    int r = bid - 8192;
    int z = r >> 10;
    const float* src = (z == 0) ? Wq : (z == 1) ? Wk : (z == 2) ? Wv : Wo;
    float sc = (z == 0) ? 0.18033688011112042f : 1.0f;   // (1/8)*log2(e) folded into Wq
    int i = ((r & 1023) * 256 + threadIdx.x) * 4;
    float4 v = *(const float4*)(src + i);
    ushort4 o;
    o.x = f2bf(v.x * sc); o.y = f2bf(v.y * sc); o.z = f2bf(v.z * sc); o.w = f2bf(v.w * sc);
    *(ushort4*)(Wb + (size_t)z * 1048576 + i) = o;
  } else {
    int i = (bid - 12288) * 256 + threadIdx.x;   // 0..131071
    int pos = i >> 5, j = i & 31;
    float invf = exp2f(-(float)j * 0.41524101186092029f);  // 10000^(-j/32)
    float ang = (float)pos * invf;
    cosT[i] = cosf(ang);
    sinT[i] = sinf(ang);
  }
}

// ---------------- fused QKV GEMM: C_z[M,N] = A[M,K] * Wz[N,K]^T for z in {0,1,2} ----------------
// Shared A staging (1x instead of 3x), 3 B-buffers, 3 acc streams -> 96 MFMAs per thread per
// barrier period (3x the split kernel; the m97-structure ~20% barrier-drain amortizes 3x).
// 512 wgs (8 bn x 64 bm), XCD-chunked swizzle (bn fastest). Epilogues: z=0 Q-RoPE, z=1 K-RoPE
// (LDS-transpose, coalesced uint4), z=2 fused V^T store — identical to the proven split kernel.
__global__ __launch_bounds__(256, 2) void k_gemm_qkv(
    const unsigned short* __restrict__ A,
    const unsigned short* __restrict__ Bw,
    unsigned short* __restrict__ obf,     // Q at +0, K at +MROWS*DMODEL
    unsigned short* __restrict__ Vt,
    const float* __restrict__ cosT, const float* __restrict__ sinT) {
  const int wg = (blockIdx.x & 7) * 64 + (blockIdx.x >> 3);
  const int bn = wg & 7, bm = wg >> 3;
  const int t = threadIdx.x;
  const int w = t >> 6, lane = t & 63;
  const int wr = w >> 1, wc = w & 1;
  const int lr = lane & 15, lg = lane >> 4;

  __shared__ __align__(16) unsigned short SM[4][128 * 64];   // A, B0, B1, B2 = 64 KB

  const unsigned short* Ab = A + (size_t)bm * 128 * DMODEL;
  const unsigned short* Bb = Bw + (size_t)bn * 128 * DMODEL;
  const int trow = t >> 3, tcol = (t & 7) * 8;

  f32x4 acc[3][4][4] = {};

  for (int k0 = 0; k0 < DMODEL; k0 += 64) {
#pragma unroll
    for (int c = 0; c < 4; ++c) {
      gload16(Ab + (size_t)(c * 32 + trow) * DMODEL + k0 + tcol, &SM[0][c * 2048 + t * 8]);
#pragma unroll
      for (int z = 0; z < 3; ++z)
        gload16(Bb + (size_t)z * 1048576 + (size_t)(c * 32 + trow) * DMODEL + k0 + tcol,
                &SM[1 + z][c * 2048 + t * 8]);
    }
    asm volatile("s_waitcnt vmcnt(0)" ::: "memory");
    __syncthreads();
#pragma unroll
    for (int kk = 0; kk < 2; ++kk) {
      short8 af[4];
#pragma unroll
      for (int mi = 0; mi < 4; ++mi)
        af[mi] = *(const short8*)&SM[0][(wr * 64 + mi * 16 + lr) * 64 + kk * 32 + lg * 8];
#pragma unroll
      for (int z = 0; z < 3; ++z) {
        short8 bfr[4];
#pragma unroll
        for (int ni = 0; ni < 4; ++ni)
          bfr[ni] = *(const short8*)&SM[1 + z][(wc * 64 + ni * 16 + lr) * 64 + kk * 32 + lg * 8];
#pragma unroll
        for (int mi = 0; mi < 4; ++mi)
#pragma unroll
          for (int ni = 0; ni < 4; ++ni)
            acc[z][mi][ni] = __builtin_amdgcn_mfma_f32_16x16x32_bf16(af[mi], bfr[ni], acc[z][mi][ni], 0, 0, 0);
      }
    }
    __syncthreads();
  }

  // ---- epilogues ----
  float* Cf = (float*)&SM[0][0];   // 64 x 128 fp32 = 32 KB (aliases SM[0..1])
#pragma unroll
  for (int z = 0; z < 2; ++z) {
    unsigned short* oz = obf + (size_t)z * MROWS * DMODEL;
#pragma unroll
    for (int half = 0; half < 2; ++half) {
      __syncthreads();   // protect Cf from the previous phase's readers
      if (wr == half) {
#pragma unroll
        for (int mi = 0; mi < 4; ++mi)
#pragma unroll
          for (int ni = 0; ni < 4; ++ni)
#pragma unroll
            for (int r = 0; r < 4; ++r) {
              int row = mi * 16 + lg * 4 + r;
              int col = (wc * 64 + ni * 16 + lr) ^ (lg << 3);   // XOR keeps writes 2-way (free)
              Cf[row * 128 + col] = acc[z][mi][ni][r];
            }
      }
      __syncthreads();
      int pr = t >> 2;
      int gm = bm * 128 + half * 64 + pr;
      int pos = gm & (NSEQ - 1);
      int xorv = ((pr >> 2) & 3) << 3;
      const float* cB = cosT + pos * 32;
      const float* sB = sinT + pos * 32;
      unsigned short* orow = oz + (size_t)gm * DMODEL + bn * 128;
#pragma unroll
      for (int k = 0; k < 4; ++k) {
        int c0 = (t & 3) * 8 + k * 32;          // logical col (8 cols = 4 rope pairs)
        int cs = c0 ^ xorv;
        float4 va = *(const float4*)&Cf[pr * 128 + cs];
        float4 vb = *(const float4*)&Cf[pr * 128 + cs + 4];
        int j0 = (c0 & 63) >> 1;
        float4 cv = *(const float4*)&cB[j0];
        float4 sv = *(const float4*)&sB[j0];
        uint4 o;
        o.x = pkc(va.x * cv.x - va.y * sv.x, va.x * sv.x + va.y * cv.x);
        o.y = pkc(va.z * cv.y - va.w * sv.y, va.z * sv.y + va.w * cv.y);
        o.z = pkc(vb.x * cv.z - vb.y * sv.z, vb.x * sv.z + vb.y * cv.z);
        o.w = pkc(vb.z * cv.w - vb.w * sv.w, vb.z * sv.w + vb.w * cv.w);
        *(uint4*)(orow + c0) = o;
      }
    }
  }
  // z = 2: fused V^T store (register-direct, lane's 4 regs = 4 consecutive n at channel gn)
#pragma unroll
  for (int mi = 0; mi < 4; ++mi)
#pragma unroll
    for (int ni = 0; ni < 4; ++ni) {
      int gm0 = bm * 128 + wr * 64 + mi * 16 + lg * 4;
      int gn = bn * 128 + wc * 64 + ni * 16 + lr;
      int b = gm0 >> 12, n = gm0 & (NSEQ - 1);
      int h = gn >> 6, d = gn & 63;
      uint2 u;
      u.x = pkc(acc[2][mi][ni][0], acc[2][mi][ni][1]);
      u.y = pkc(acc[2][mi][ni][2], acc[2][mi][ni][3]);
      *(uint2*)(Vt + ((size_t)((b * 16 + h) * 64 + d)) * NSEQ + n) = u;
    }
}

// ---------------- out-projection GEMM (proven kernel, mode 3 only) ----------------
__global__ __launch_bounds__(256) void k_gemm_bt(
    const unsigned short* __restrict__ A,
    const unsigned short* __restrict__ Bw,
    float* __restrict__ of32,
    int K) {
  const int N = DMODEL;
  const int q8 = gridDim.x >> 3;
  const int wg = (blockIdx.x & 7) * q8 + (blockIdx.x >> 3);
  const int rr = wg & 511;
  const int bn = rr & 7, bm = rr >> 3;

  const int t = threadIdx.x;
  const int w = t >> 6, lane = t & 63;
  const int wr = w >> 1, wc = w & 1;
  const int lr = lane & 15, lg = lane >> 4;

  __shared__ __align__(16) unsigned short SM[2][128 * 64];
  unsigned short* Al = SM[0];
  unsigned short* Bl = SM[1];

  const unsigned short* Ab = A + (size_t)bm * 128 * K;
  const unsigned short* Bb = Bw + (size_t)bn * 128 * K;
  const int trow = t >> 3, tcol = (t & 7) * 8;

  f32x4 acc[4][4] = {};

  for (int k0 = 0; k0 < K; k0 += 64) {
#pragma unroll
    for (int c = 0; c < 4; ++c) {
      gload16(Ab + (size_t)(c * 32 + trow) * K + k0 + tcol, &Al[c * 2048 + t * 8]);
      gload16(Bb + (size_t)(c * 32 + trow) * K + k0 + tcol, &Bl[c * 2048 + t * 8]);
    }
    asm volatile("s_waitcnt vmcnt(0)" ::: "memory");
    __syncthreads();
#pragma unroll
    for (int kk = 0; kk < 2; ++kk) {
      short8 af[4], bfr[4];
#pragma unroll
      for (int mi = 0; mi < 4; ++mi)
        af[mi] = *(const short8*)&Al[(wr * 64 + mi * 16 + lr) * 64 + kk * 32 + lg * 8];
#pragma unroll
      for (int ni = 0; ni < 4; ++ni)
        bfr[ni] = *(const short8*)&Bl[(wc * 64 + ni * 16 + lr) * 64 + kk * 32 + lg * 8];
#pragma unroll
      for (int mi = 0; mi < 4; ++mi)
#pragma unroll
        for (int ni = 0; ni < 4; ++ni)
          acc[mi][ni] = __builtin_amdgcn_mfma_f32_16x16x32_bf16(af[mi], bfr[ni], acc[mi][ni], 0, 0, 0);
    }
    __syncthreads();
  }

  // fp32 store via LDS transpose (coalesced float4)
  float* Cf = (float*)&SM[0][0];
#pragma unroll
  for (int half = 0; half < 2; ++half) {
    if (half) __syncthreads();
    if (wr == half) {
#pragma unroll
      for (int mi = 0; mi < 4; ++mi)
#pragma unroll
        for (int ni = 0; ni < 4; ++ni)
#pragma unroll
          for (int r = 0; r < 4; ++r) {
            int row = mi * 16 + lg * 4 + r;
            int col = (wc * 64 + ni * 16 + lr) ^ (lg << 3);
            Cf[row * 128 + col] = acc[mi][ni][r];
          }
    }
    __syncthreads();
    int pr = t >> 2;
    int gm = bm * 128 + half * 64 + pr;
    int xorv = ((pr >> 2) & 3) << 3;
    float* orow = of32 + (size_t)gm * N + bn * 128;
#pragma unroll
    for (int k = 0; k < 4; ++k) {
      int c0 = (t & 3) * 8 + k * 32;
      int cs = c0 ^ xorv;
      float4 va = *(const float4*)&Cf[pr * 128 + cs];
      float4 vb = *(const float4*)&Cf[pr * 128 + cs + 4];
      *(float4*)(orow + c0) = va;
      *(float4*)(orow + c0 + 4) = vb;
    }
  }
}

// ---------------- causal flash attention, swapped-operand (S^T / O^T), fixed-max ----------------
// Best measured (98.2 us). Grid 512 uniform pairs (qt = 31-pq then pq), 4 waves x 32 q,
// KVBLK=64 double-buffered, in-register P relayout (permlane32/16_swap), v_cvt_pk_bf16_f32
// packing, P = exp2(S) fixed-max softmax, l via ones-A MFMA.
__global__ __launch_bounds__(256, 2) void k_attn12(
    const unsigned short* __restrict__ Qb,
    const unsigned short* __restrict__ Kb,
    const unsigned short* __restrict__ Vtg,
    unsigned short* __restrict__ AO) {
  const int id = blockIdx.x;
  const int bh = id & 31;
  const int pq = id >> 5;            // 0..15
  const int b = bh >> 4, h = bh & 15;
  const int t = threadIdx.x;
  const int w = t >> 6, lane = t & 63;
  const int lr = lane & 15, hi4 = lane >> 4;
  const size_t rowbase = (size_t)b * NSEQ;

  __shared__ __align__(16) unsigned short Kl[2][64 * 64];
  __shared__ __align__(16) unsigned short Vl[2][64 * 64];
  __shared__ __align__(16) unsigned short Pl[4][16 * 64];   // epilogue-only

  const int pswz = (lr & 7) << 3;

  short8 ones;
#pragma unroll
  for (int i = 0; i < 8; ++i) ones[i] = (short)0x3F80;   // bf16 1.0

#define STAGE(buf, kv0)                                                                   \
  {                                                                                       \
    _Pragma("unroll")                                                                     \
    for (int it = 0; it < 2; ++it) {                                                      \
      int c = t + it * 256;                                                               \
      int row = c >> 3, sg = (c & 7) ^ (row & 7);                                         \
      gload16(Kb + (rowbase + (kv0) + row) * DMODEL + h * 64 + sg * 8, &Kl[buf][c * 8]);  \
      gload16(Vtg + ((size_t)bh * 64 + row) * NSEQ + (kv0) + sg * 8, &Vl[buf][c * 8]);    \
    }                                                                                     \
  }

#pragma unroll
  for (int qi = 0; qi < 2; ++qi) {
    const int qt = qi ? pq : (31 - pq);
    const int q0w = qt * 128 + w * 32;

    short8 qf[2][2];
#pragma unroll
    for (int sub = 0; sub < 2; ++sub) {
      const unsigned short* qp = Qb + (rowbase + q0w + sub * 16 + lr) * DMODEL + h * 64 + hi4 * 8;
#pragma unroll
      for (int s = 0; s < 2; ++s)
        qf[sub][s] = *(const short8*)(qp + s * 32);
    }

    f32x4 oacc[2][4] = {};
    f32x4 lacc[2] = {};
    const int nkv = (qt + 1) * 2;

    STAGE(0, 0);
    asm volatile("s_waitcnt vmcnt(0)" ::: "memory");
    __syncthreads();

    for (int ib = 0; ib < nkv; ++ib) {
      const int kv0 = ib * 64, cur = ib & 1;
      if (ib + 1 < nkv) STAGE(cur ^ 1, kv0 + 64);

      if (kv0 <= q0w + 31) {
        short8 Kf[4][2], Vf[2][4];
#pragma unroll
        for (int t4 = 0; t4 < 4; ++t4)
#pragma unroll
          for (int s = 0; s < 2; ++s)
            Kf[t4][s] = *(const short8*)&Kl[cur][(t4 * 16 + lr) * 64 + (((s * 4 + hi4) ^ (lr & 7)) * 8)];
#pragma unroll
        for (int c = 0; c < 2; ++c)
#pragma unroll
          for (int dt = 0; dt < 4; ++dt)
            Vf[c][dt] = *(const short8*)&Vl[cur][(dt * 16 + lr) * 64 + (((c * 4 + hi4) ^ (lr & 7)) * 8)];

#pragma unroll
        for (int sub = 0; sub < 2; ++sub) {
          const int qs = q0w + sub * 16;
          const int qlane = qs + lr;
          f32x4 sa[4];
          const f32x4 zz = {0.f, 0.f, 0.f, 0.f};
          __builtin_amdgcn_s_setprio(1);
#pragma unroll
          for (int t4 = 0; t4 < 4; ++t4) {
            f32x4 x = __builtin_amdgcn_mfma_f32_16x16x32_bf16(Kf[t4][0], qf[sub][0], zz, 0, 0, 0);
            sa[t4] = __builtin_amdgcn_mfma_f32_16x16x32_bf16(Kf[t4][1], qf[sub][1], x, 0, 0, 0);
          }
          __builtin_amdgcn_s_setprio(0);
          if (kv0 + 63 > qs) {
#pragma unroll
            for (int t4 = 0; t4 < 4; ++t4)
#pragma unroll
              for (int r = 0; r < 4; ++r)
                if (kv0 + t4 * 16 + hi4 * 4 + r > qlane) sa[t4][r] = -1e30f;
          }
#pragma unroll
          for (int t4 = 0; t4 < 4; ++t4)
#pragma unroll
            for (int r = 0; r < 4; ++r)
              sa[t4][r] = __builtin_amdgcn_exp2f(sa[t4][r]);

          // pack via HW cvt_pk: a_{2t4} = P[kv=16t4+4hi4+{0,1}], a_{2t4+1} = +{2,3}
          unsigned a0 = pkc(sa[0][0], sa[0][1]), a1 = pkc(sa[0][2], sa[0][3]);
          unsigned a2 = pkc(sa[1][0], sa[1][1]), a3 = pkc(sa[1][2], sa[1][3]);
          unsigned a4 = pkc(sa[2][0], sa[2][1]), a5 = pkc(sa[2][2], sa[2][3]);
          unsigned a6 = pkc(sa[3][0], sa[3][1]), a7 = pkc(sa[3][2], sa[3][3]);
          // in-register 4-lane-group transpose -> B-operand words
          unsigned w0, w1, w2, w3, x0, x1, x2, x3;
          pexch(a0, a2, w0, w2);
          pexch(a1, a3, w1, w3);
          pexch(a4, a6, x0, x2);
          pexch(a5, a7, x1, x3);
          union { uint4 u; short8 s; } P0, P1;
          P0.u.x = w0; P0.u.y = w1; P0.u.z = w2; P0.u.w = w3;
          P1.u.x = x0; P1.u.y = x1; P1.u.z = x2; P1.u.w = x3;
          short8 pf0 = P0.s;
          short8 pf1 = P1.s;

          __builtin_amdgcn_s_setprio(1);
#pragma unroll
          for (int dt = 0; dt < 4; ++dt) {
            oacc[sub][dt] = __builtin_amdgcn_mfma_f32_16x16x32_bf16(Vf[0][dt], pf0, oacc[sub][dt], 0, 0, 0);
            oacc[sub][dt] = __builtin_amdgcn_mfma_f32_16x16x32_bf16(Vf[1][dt], pf1, oacc[sub][dt], 0, 0, 0);
          }
          lacc[sub] = __builtin_amdgcn_mfma_f32_16x16x32_bf16(ones, pf0, lacc[sub], 0, 0, 0);
          lacc[sub] = __builtin_amdgcn_mfma_f32_16x16x32_bf16(ones, pf1, lacc[sub], 0, 0, 0);
          __builtin_amdgcn_s_setprio(0);
        }
      }
      asm volatile("s_waitcnt vmcnt(0)" ::: "memory");
      __syncthreads();
    }

    // epilogue: O^T/l -> LDS transpose (swizzled) -> coalesced bf16 stores
#pragma unroll
    for (int sub = 0; sub < 2; ++sub) {
      float inv = 1.f / lacc[sub][0];
#pragma unroll
      for (int dt = 0; dt < 4; ++dt) {
        uint2 u;
        u.x = pkc(oacc[sub][dt][0] * inv, oacc[sub][dt][1] * inv);
        u.y = pkc(oacc[sub][dt][2] * inv, oacc[sub][dt][3] * inv);
        *(uint2*)&Pl[w][lr * 64 + ((dt * 16 + hi4 * 4) ^ pswz)] = u;
      }
      asm volatile("s_waitcnt lgkmcnt(0)" ::: "memory");
      __builtin_amdgcn_sched_barrier(0);
      int q2 = lane >> 2, ch = (lane & 3) * 16;
      int qswz = (q2 & 7) << 3;
      uint4 r0 = *(const uint4*)&Pl[w][q2 * 64 + (ch ^ qswz)];
      uint4 r1 = *(const uint4*)&Pl[w][q2 * 64 + ((ch + 8) ^ qswz)];
      unsigned short* op = AO + (rowbase + q0w + sub * 16 + q2) * DMODEL + h * 64 + ch;
      *(uint4*)op = r0;
      *(uint4*)(op + 8) = r1;
      __syncthreads();
    }
  }
}

extern "C" void kernel_launch(void* const* d_in, const int* in_sizes, int n_in,
                              void* d_out, int out_size, void* d_ws, size_t ws_size,
                              hipStream_t stream) {
  const float* x  = (const float*)d_in[0];
  const float* Wq = (const float*)d_in[1];
  const float* Wk = (const float*)d_in[2];
  const float* Wv = (const float*)d_in[3];
  const float* Wo = (const float*)d_in[4];
  float* out = (float*)d_out;
  char* ws = (char*)d_ws;

  // ws layout (bytes):
  unsigned short* xb  = (unsigned short*)(ws);                 // 16 MB
  unsigned short* Wb  = (unsigned short*)(ws + 16777216);      // 4 x 2 MB (q,k,v,o)
  unsigned short* Qb  = (unsigned short*)(ws + 25165824);      // 16 MB
  unsigned short* Kb  = Qb + 8388608;                          // 16 MB @ 41943040
  unsigned short* Vtg = (unsigned short*)(ws + 58720256);      // 16 MB (V^T [bh*64+d][n])
  unsigned short* AO  = (unsigned short*)(ws + 75497472);      // 16 MB
  float* cosT = (float*)(ws + 92274688);                       // 512 KB
  float* sinT = (float*)(ws + 92798976);                       // 512 KB

  // fused prep: x/weight converts + RoPE tables in one dispatch
  k_prep<<<12800, 256, 0, stream>>>(x, Wq, Wk, Wv, Wo, xb, Wb, cosT, sinT);

  // fused Q/K/V projections in ONE kernel (shared A staging, 3 acc streams);
  // Q/K RoPE epilogues, V stored transposed to Vtg
  k_gemm_qkv<<<512, 256, 0, stream>>>(xb, Wb, Qb, Vtg, cosT, sinT);

  // causal flash attention (uniform pairs, in-register P exchange, cvt_pk packing)
  k_attn12<<<512, 256, 0, stream>>>(Qb, Kb, Vtg, AO);

  // output projection, fp32 out
  k_gemm_bt<<<512, 256, 0, stream>>>(AO, Wb + 3145728, out, DMODEL);
}

// Round 21
// 189.213 us; speedup vs baseline: 1.1634x; 1.0098x over previous
//
#include <hip/hip_runtime.h>
#include <hip/hip_bf16.h>
#include <stdint.h>

typedef __attribute__((ext_vector_type(8))) short short8;
typedef __attribute__((ext_vector_type(4))) float f32x4;
typedef __attribute__((ext_vector_type(2))) unsigned uint32x2;

#define NSEQ 4096
#define DMODEL 1024
#define MROWS 8192   // B*N

__device__ __forceinline__ unsigned short f2bf(float f) {
  union { float f; unsigned u; } v; v.f = f;
  unsigned r = v.u + 0x7fffu + ((v.u >> 16) & 1u);
  return (unsigned short)(r >> 16);
}

// packed RNE bf16x2 via the HW instruction (identical rounding to f2bf; 1 instr vs ~10)
__device__ __forceinline__ unsigned pkc(float lo, float hi) {
  unsigned r;
  asm("v_cvt_pk_bf16_f32 %0, %1, %2" : "=v"(r) : "v"(lo), "v"(hi));
  return r;
}

__device__ __forceinline__ void gload16(const unsigned short* g, unsigned short* l) {
  __builtin_amdgcn_global_load_lds(
      (const __attribute__((address_space(1))) unsigned int*)g,
      (__attribute__((address_space(3))) unsigned int*)l, 16, 0, 0);
}

// 4-lane-group (stride-16) transpose step: from (x, y) produce the two B-operand words.
__device__ __forceinline__ void pexch(unsigned x, unsigned y, unsigned& w_lo, unsigned& w_hi) {
  uint32x2 t = __builtin_amdgcn_permlane32_swap(x, y, false, false);
  uint32x2 u = __builtin_amdgcn_permlane16_swap(t[0], t[1], false, false);
  w_lo = u[0];
  w_hi = u[1];
}

// ---------------- fused prep: x convert (bids 0..8191), weight converts (8192..12287,
// Wq scaled by log2e/8), RoPE tables (12288..12799) ----------------
__global__ void k_prep(const float* __restrict__ x,
                       const float* __restrict__ Wq, const float* __restrict__ Wk,
                       const float* __restrict__ Wv, const float* __restrict__ Wo,
                       unsigned short* __restrict__ xb, unsigned short* __restrict__ Wb,
                       float* __restrict__ cosT, float* __restrict__ sinT) {
  int bid = blockIdx.x;
  if (bid < 8192) {
    int i = (bid * 256 + threadIdx.x) * 4;
    float4 v = *(const float4*)(x + i);
    ushort4 o;
    o.x = f2bf(v.x); o.y = f2bf(v.y); o.z = f2bf(v.z); o.w = f2bf(v.w);
    *(ushort4*)(xb + i) = o;
  } else if (bid < 12288) {
    int r = bid - 8192;
    int z = r >> 10;
    const float* src = (z == 0) ? Wq : (z == 1) ? Wk : (z == 2) ? Wv : Wo;
    float sc = (z == 0) ? 0.18033688011112042f : 1.0f;   // (1/8)*log2(e) folded into Wq
    int i = ((r & 1023) * 256 + threadIdx.x) * 4;
    float4 v = *(const float4*)(src + i);
    ushort4 o;
    o.x = f2bf(v.x * sc); o.y = f2bf(v.y * sc); o.z = f2bf(v.z * sc); o.w = f2bf(v.w * sc);
    *(ushort4*)(Wb + (size_t)z * 1048576 + i) = o;
  } else {
    int i = (bid - 12288) * 256 + threadIdx.x;   // 0..131071
    int pos = i >> 5, j = i & 31;
    float invf = exp2f(-(float)j * 0.41524101186092029f);  // 10000^(-j/32)
    float ang = (float)pos * invf;
    cosT[i] = cosf(ang);
    sinT[i] = sinf(ang);
  }
}

// ---------------- fused QKV GEMM: C_z[M,N] = A[M,K] * Wz[N,K]^T for z in {0,1,2} ----------------
// Shared A staging (1x instead of 3x), 3 B-buffers, 3 acc streams -> 96 MFMAs per thread per
// barrier period. 512 wgs (8 bn x 64 bm), XCD-chunked swizzle. Epilogues: z=0/1 RoPE via LDS
// transpose (coalesced uint4), z=2 fused V^T store.
__global__ __launch_bounds__(256, 2) void k_gemm_qkv(
    const unsigned short* __restrict__ A,
    const unsigned short* __restrict__ Bw,
    unsigned short* __restrict__ obf,     // Q at +0, K at +MROWS*DMODEL
    unsigned short* __restrict__ Vt,
    const float* __restrict__ cosT, const float* __restrict__ sinT) {
  const int wg = (blockIdx.x & 7) * 64 + (blockIdx.x >> 3);
  const int bn = wg & 7, bm = wg >> 3;
  const int t = threadIdx.x;
  const int w = t >> 6, lane = t & 63;
  const int wr = w >> 1, wc = w & 1;
  const int lr = lane & 15, lg = lane >> 4;

  __shared__ __align__(16) unsigned short SM[4][128 * 64];   // A, B0, B1, B2 = 64 KB

  const unsigned short* Ab = A + (size_t)bm * 128 * DMODEL;
  const unsigned short* Bb = Bw + (size_t)bn * 128 * DMODEL;
  const int trow = t >> 3, tcol = (t & 7) * 8;

  f32x4 acc[3][4][4] = {};

  for (int k0 = 0; k0 < DMODEL; k0 += 64) {
#pragma unroll
    for (int c = 0; c < 4; ++c) {
      gload16(Ab + (size_t)(c * 32 + trow) * DMODEL + k0 + tcol, &SM[0][c * 2048 + t * 8]);
#pragma unroll
      for (int z = 0; z < 3; ++z)
        gload16(Bb + (size_t)z * 1048576 + (size_t)(c * 32 + trow) * DMODEL + k0 + tcol,
                &SM[1 + z][c * 2048 + t * 8]);
    }
    asm volatile("s_waitcnt vmcnt(0)" ::: "memory");
    __syncthreads();
#pragma unroll
    for (int kk = 0; kk < 2; ++kk) {
      short8 af[4];
#pragma unroll
      for (int mi = 0; mi < 4; ++mi)
        af[mi] = *(const short8*)&SM[0][(wr * 64 + mi * 16 + lr) * 64 + kk * 32 + lg * 8];
#pragma unroll
      for (int z = 0; z < 3; ++z) {
        short8 bfr[4];
#pragma unroll
        for (int ni = 0; ni < 4; ++ni)
          bfr[ni] = *(const short8*)&SM[1 + z][(wc * 64 + ni * 16 + lr) * 64 + kk * 32 + lg * 8];
#pragma unroll
        for (int mi = 0; mi < 4; ++mi)
#pragma unroll
          for (int ni = 0; ni < 4; ++ni)
            acc[z][mi][ni] = __builtin_amdgcn_mfma_f32_16x16x32_bf16(af[mi], bfr[ni], acc[z][mi][ni], 0, 0, 0);
      }
    }
    __syncthreads();
  }

  // ---- epilogues ----
  float* Cf = (float*)&SM[0][0];   // 64 x 128 fp32 = 32 KB (aliases SM[0..1])
#pragma unroll
  for (int z = 0; z < 2; ++z) {
    unsigned short* oz = obf + (size_t)z * MROWS * DMODEL;
#pragma unroll
    for (int half = 0; half < 2; ++half) {
      __syncthreads();   // protect Cf from the previous phase's readers
      if (wr == half) {
#pragma unroll
        for (int mi = 0; mi < 4; ++mi)
#pragma unroll
          for (int ni = 0; ni < 4; ++ni)
#pragma unroll
            for (int r = 0; r < 4; ++r) {
              int row = mi * 16 + lg * 4 + r;
              int col = (wc * 64 + ni * 16 + lr) ^ (lg << 3);   // XOR keeps writes 2-way (free)
              Cf[row * 128 + col] = acc[z][mi][ni][r];
            }
      }
      __syncthreads();
      int pr = t >> 2;
      int gm = bm * 128 + half * 64 + pr;
      int pos = gm & (NSEQ - 1);
      int xorv = ((pr >> 2) & 3) << 3;
      const float* cB = cosT + pos * 32;
      const float* sB = sinT + pos * 32;
      unsigned short* orow = oz + (size_t)gm * DMODEL + bn * 128;
#pragma unroll
      for (int k = 0; k < 4; ++k) {
        int c0 = (t & 3) * 8 + k * 32;          // logical col (8 cols = 4 rope pairs)
        int cs = c0 ^ xorv;
        float4 va = *(const float4*)&Cf[pr * 128 + cs];
        float4 vb = *(const float4*)&Cf[pr * 128 + cs + 4];
        int j0 = (c0 & 63) >> 1;
        float4 cv = *(const float4*)&cB[j0];
        float4 sv = *(const float4*)&sB[j0];
        uint4 o;
        o.x = pkc(va.x * cv.x - va.y * sv.x, va.x * sv.x + va.y * cv.x);
        o.y = pkc(va.z * cv.y - va.w * sv.y, va.z * sv.y + va.w * cv.y);
        o.z = pkc(vb.x * cv.z - vb.y * sv.z, vb.x * sv.z + vb.y * cv.z);
        o.w = pkc(vb.z * cv.w - vb.w * sv.w, vb.z * sv.w + vb.w * cv.w);
        *(uint4*)(orow + c0) = o;
      }
    }
  }
  // z = 2: fused V^T store (register-direct, lane's 4 regs = 4 consecutive n at channel gn)
#pragma unroll
  for (int mi = 0; mi < 4; ++mi)
#pragma unroll
    for (int ni = 0; ni < 4; ++ni) {
      int gm0 = bm * 128 + wr * 64 + mi * 16 + lg * 4;
      int gn = bn * 128 + wc * 64 + ni * 16 + lr;
      int b = gm0 >> 12, n = gm0 & (NSEQ - 1);
      int h = gn >> 6, d = gn & 63;
      uint2 u;
      u.x = pkc(acc[2][mi][ni][0], acc[2][mi][ni][1]);
      u.y = pkc(acc[2][mi][ni][2], acc[2][mi][ni][3]);
      *(uint2*)(Vt + ((size_t)((b * 16 + h) * 64 + d)) * NSEQ + n) = u;
    }
}

// ---------------- out-projection GEMM (proven kernel, fp32 LDS-transposed store) ----------------
__global__ __launch_bounds__(256) void k_gemm_bt(
    const unsigned short* __restrict__ A,
    const unsigned short* __restrict__ Bw,
    float* __restrict__ of32,
    int K) {
  const int N = DMODEL;
  const int q8 = gridDim.x >> 3;
  const int wg = (blockIdx.x & 7) * q8 + (blockIdx.x >> 3);
  const int rr = wg & 511;
  const int bn = rr & 7, bm = rr >> 3;

  const int t = threadIdx.x;
  const int w = t >> 6, lane = t & 63;
  const int wr = w >> 1, wc = w & 1;
  const int lr = lane & 15, lg = lane >> 4;

  __shared__ __align__(16) unsigned short SM[2][128 * 64];
  unsigned short* Al = SM[0];
  unsigned short* Bl = SM[1];

  const unsigned short* Ab = A + (size_t)bm * 128 * K;
  const unsigned short* Bb = Bw + (size_t)bn * 128 * K;
  const int trow = t >> 3, tcol = (t & 7) * 8;

  f32x4 acc[4][4] = {};

  for (int k0 = 0; k0 < K; k0 += 64) {
#pragma unroll
    for (int c = 0; c < 4; ++c) {
      gload16(Ab + (size_t)(c * 32 + trow) * K + k0 + tcol, &Al[c * 2048 + t * 8]);
      gload16(Bb + (size_t)(c * 32 + trow) * K + k0 + tcol, &Bl[c * 2048 + t * 8]);
    }
    asm volatile("s_waitcnt vmcnt(0)" ::: "memory");
    __syncthreads();
#pragma unroll
    for (int kk = 0; kk < 2; ++kk) {
      short8 af[4], bfr[4];
#pragma unroll
      for (int mi = 0; mi < 4; ++mi)
        af[mi] = *(const short8*)&Al[(wr * 64 + mi * 16 + lr) * 64 + kk * 32 + lg * 8];
#pragma unroll
      for (int ni = 0; ni < 4; ++ni)
        bfr[ni] = *(const short8*)&Bl[(wc * 64 + ni * 16 + lr) * 64 + kk * 32 + lg * 8];
#pragma unroll
      for (int mi = 0; mi < 4; ++mi)
#pragma unroll
        for (int ni = 0; ni < 4; ++ni)
          acc[mi][ni] = __builtin_amdgcn_mfma_f32_16x16x32_bf16(af[mi], bfr[ni], acc[mi][ni], 0, 0, 0);
    }
    __syncthreads();
  }

  // fp32 store via LDS transpose (coalesced float4)
  float* Cf = (float*)&SM[0][0];
#pragma unroll
  for (int half = 0; half < 2; ++half) {
    if (half) __syncthreads();
    if (wr == half) {
#pragma unroll
      for (int mi = 0; mi < 4; ++mi)
#pragma unroll
        for (int ni = 0; ni < 4; ++ni)
#pragma unroll
          for (int r = 0; r < 4; ++r) {
            int row = mi * 16 + lg * 4 + r;
            int col = (wc * 64 + ni * 16 + lr) ^ (lg << 3);
            Cf[row * 128 + col] = acc[mi][ni][r];
          }
    }
    __syncthreads();
    int pr = t >> 2;
    int gm = bm * 128 + half * 64 + pr;
    int xorv = ((pr >> 2) & 3) << 3;
    float* orow = of32 + (size_t)gm * N + bn * 128;
#pragma unroll
    for (int k = 0; k < 4; ++k) {
      int c0 = (t & 3) * 8 + k * 32;
      int cs = c0 ^ xorv;
      float4 va = *(const float4*)&Cf[pr * 128 + cs];
      float4 vb = *(const float4*)&Cf[pr * 128 + cs + 4];
      *(float4*)(orow + c0) = va;
      *(float4*)(orow + c0 + 4) = vb;
    }
  }
}

// ---------------- causal flash attention: dual-q-tile shared kv-sweep ----------------
// R21: block (bh, pq) processes BOTH q-tiles qtA = 31-pq and qtB = pq in ONE kv sweep
// (tile B's kv range is a subset of tile A's). Barrier/staging periods per block: 66 ->
// 64-2pq (34..64); per co-resident CU pair: 132 -> 84..112. Overlap steps run both tiles'
// MFMA per period — the same amortization mechanism as the fused QKV GEMM (R20, -26us).
// K/V staged once (FETCH ~-25%). VGPR ~160 (launch_bounds(256,2) cap 256); all tile/sub
// indices compile-time (unrolled). Swapped-operand S^T/O^T, in-register P relayout
// (permlane32/16_swap), cvt_pk packing, P = exp2(S) fixed-max softmax, l via ones-A MFMA.
__global__ __launch_bounds__(256, 2) void k_attn15(
    const unsigned short* __restrict__ Qb,
    const unsigned short* __restrict__ Kb,
    const unsigned short* __restrict__ Vtg,
    unsigned short* __restrict__ AO) {
  const int id = blockIdx.x;
  const int bh = id & 31;
  const int pq = id >> 5;            // 0..15; low ids (big sweeps) dispatch first
  const int b = bh >> 4, h = bh & 15;
  const int t = threadIdx.x;
  const int w = t >> 6, lane = t & 63;
  const int lr = lane & 15, hi4 = lane >> 4;
  const size_t rowbase = (size_t)b * NSEQ;

  __shared__ __align__(16) unsigned short Kl[2][64 * 64];
  __shared__ __align__(16) unsigned short Vl[2][64 * 64];
  __shared__ __align__(16) unsigned short Pl[4][16 * 64];   // epilogue-only

  const int pswz = (lr & 7) << 3;

  short8 ones;
#pragma unroll
  for (int i = 0; i < 8; ++i) ones[i] = (short)0x3F80;   // bf16 1.0

#define STAGE(buf, kv0)                                                                   \
  {                                                                                       \
    _Pragma("unroll")                                                                     \
    for (int it = 0; it < 2; ++it) {                                                      \
      int c = t + it * 256;                                                               \
      int row = c >> 3, sg = (c & 7) ^ (row & 7);                                         \
      gload16(Kb + (rowbase + (kv0) + row) * DMODEL + h * 64 + sg * 8, &Kl[buf][c * 8]);  \
      gload16(Vtg + ((size_t)bh * 64 + row) * NSEQ + (kv0) + sg * 8, &Vl[buf][c * 8]);    \
    }                                                                                     \
  }

  // q-row bases for the two tiles this block owns
  int q0t[2];
  q0t[0] = (31 - pq) * 128 + w * 32;   // tile A (big)
  q0t[1] = pq * 128 + w * 32;          // tile B (small; kv range subset of A's)

  // Q fragments: [tile][sub][khalf]
  short8 qf[2][2][2];
#pragma unroll
  for (int tt = 0; tt < 2; ++tt)
#pragma unroll
    for (int sub = 0; sub < 2; ++sub) {
      const unsigned short* qp = Qb + (rowbase + q0t[tt] + sub * 16 + lr) * DMODEL + h * 64 + hi4 * 8;
#pragma unroll
      for (int s = 0; s < 2; ++s)
        qf[tt][sub][s] = *(const short8*)(qp + s * 32);
    }

  f32x4 oacc[2][2][4] = {};
  f32x4 lacc[2][2] = {};
  const int nkv = (32 - pq) * 2;   // one sweep covers both tiles

  STAGE(0, 0);
  asm volatile("s_waitcnt vmcnt(0)" ::: "memory");
  __syncthreads();

  for (int ib = 0; ib < nkv; ++ib) {
    const int kv0 = ib * 64, cur = ib & 1;
    if (ib + 1 < nkv) STAGE(cur ^ 1, kv0 + 64);

    // shared K/V fragments for this step
    short8 Kf[4][2], Vf[2][4];
#pragma unroll
    for (int t4 = 0; t4 < 4; ++t4)
#pragma unroll
      for (int s = 0; s < 2; ++s)
        Kf[t4][s] = *(const short8*)&Kl[cur][(t4 * 16 + lr) * 64 + (((s * 4 + hi4) ^ (lr & 7)) * 8)];
#pragma unroll
    for (int c = 0; c < 2; ++c)
#pragma unroll
      for (int dt = 0; dt < 4; ++dt)
        Vf[c][dt] = *(const short8*)&Vl[cur][(dt * 16 + lr) * 64 + (((c * 4 + hi4) ^ (lr & 7)) * 8)];

#pragma unroll
    for (int tt = 0; tt < 2; ++tt) {
      const int q0w = q0t[tt];
      if (kv0 <= q0w + 31) {
#pragma unroll
        for (int sub = 0; sub < 2; ++sub) {
          const int qs = q0w + sub * 16;
          const int qlane = qs + lr;
          f32x4 sa[4];
          const f32x4 zz = {0.f, 0.f, 0.f, 0.f};
          __builtin_amdgcn_s_setprio(1);
#pragma unroll
          for (int t4 = 0; t4 < 4; ++t4) {
            f32x4 x = __builtin_amdgcn_mfma_f32_16x16x32_bf16(Kf[t4][0], qf[tt][sub][0], zz, 0, 0, 0);
            sa[t4] = __builtin_amdgcn_mfma_f32_16x16x32_bf16(Kf[t4][1], qf[tt][sub][1], x, 0, 0, 0);
          }
          __builtin_amdgcn_s_setprio(0);
          if (kv0 + 63 > qs) {
#pragma unroll
            for (int t4 = 0; t4 < 4; ++t4)
#pragma unroll
              for (int r = 0; r < 4; ++r)
                if (kv0 + t4 * 16 + hi4 * 4 + r > qlane) sa[t4][r] = -1e30f;
          }
#pragma unroll
          for (int t4 = 0; t4 < 4; ++t4)
#pragma unroll
            for (int r = 0; r < 4; ++r)
              sa[t4][r] = __builtin_amdgcn_exp2f(sa[t4][r]);

          // pack via HW cvt_pk, then in-register 4-lane-group transpose -> B-operand words
          unsigned a0 = pkc(sa[0][0], sa[0][1]), a1 = pkc(sa[0][2], sa[0][3]);
          unsigned a2 = pkc(sa[1][0], sa[1][1]), a3 = pkc(sa[1][2], sa[1][3]);
          unsigned a4 = pkc(sa[2][0], sa[2][1]), a5 = pkc(sa[2][2], sa[2][3]);
          unsigned a6 = pkc(sa[3][0], sa[3][1]), a7 = pkc(sa[3][2], sa[3][3]);
          unsigned w0, w1, w2, w3, x0, x1, x2, x3;
          pexch(a0, a2, w0, w2);
          pexch(a1, a3, w1, w3);
          pexch(a4, a6, x0, x2);
          pexch(a5, a7, x1, x3);
          union { uint4 u; short8 s; } P0, P1;
          P0.u.x = w0; P0.u.y = w1; P0.u.z = w2; P0.u.w = w3;
          P1.u.x = x0; P1.u.y = x1; P1.u.z = x2; P1.u.w = x3;
          short8 pf0 = P0.s;
          short8 pf1 = P1.s;

          __builtin_amdgcn_s_setprio(1);
#pragma unroll
          for (int dt = 0; dt < 4; ++dt) {
            oacc[tt][sub][dt] = __builtin_amdgcn_mfma_f32_16x16x32_bf16(Vf[0][dt], pf0, oacc[tt][sub][dt], 0, 0, 0);
            oacc[tt][sub][dt] = __builtin_amdgcn_mfma_f32_16x16x32_bf16(Vf[1][dt], pf1, oacc[tt][sub][dt], 0, 0, 0);
          }
          lacc[tt][sub] = __builtin_amdgcn_mfma_f32_16x16x32_bf16(ones, pf0, lacc[tt][sub], 0, 0, 0);
          lacc[tt][sub] = __builtin_amdgcn_mfma_f32_16x16x32_bf16(ones, pf1, lacc[tt][sub], 0, 0, 0);
          __builtin_amdgcn_s_setprio(0);
        }
      }
    }
    asm volatile("s_waitcnt vmcnt(0)" ::: "memory");
    __syncthreads();
  }

  // epilogue: O^T/l -> per-wave LDS transpose (swizzled) -> coalesced bf16 stores.
  // Pl[w] is wave-private; wave-internal lgkmcnt ordering suffices (R17-validated).
#pragma unroll
  for (int tt = 0; tt < 2; ++tt)
#pragma unroll
    for (int sub = 0; sub < 2; ++sub) {
      float inv = 1.f / lacc[tt][sub][0];
#pragma unroll
      for (int dt = 0; dt < 4; ++dt) {
        uint2 u;
        u.x = pkc(oacc[tt][sub][dt][0] * inv, oacc[tt][sub][dt][1] * inv);
        u.y = pkc(oacc[tt][sub][dt][2] * inv, oacc[tt][sub][dt][3] * inv);
        *(uint2*)&Pl[w][lr * 64 + ((dt * 16 + hi4 * 4) ^ pswz)] = u;
      }
      asm volatile("s_waitcnt lgkmcnt(0)" ::: "memory");
      __builtin_amdgcn_sched_barrier(0);
      int q2 = lane >> 2, ch = (lane & 3) * 16;
      int qswz = (q2 & 7) << 3;
      uint4 r0 = *(const uint4*)&Pl[w][q2 * 64 + (ch ^ qswz)];
      uint4 r1 = *(const uint4*)&Pl[w][q2 * 64 + ((ch + 8) ^ qswz)];
      unsigned short* op = AO + (rowbase + q0t[tt] + sub * 16 + q2) * DMODEL + h * 64 + ch;
      *(uint4*)op = r0;
      *(uint4*)(op + 8) = r1;
      asm volatile("s_waitcnt lgkmcnt(0)" ::: "memory");
      __builtin_amdgcn_sched_barrier(0);
    }
}

extern "C" void kernel_launch(void* const* d_in, const int* in_sizes, int n_in,
                              void* d_out, int out_size, void* d_ws, size_t ws_size,
                              hipStream_t stream) {
  const float* x  = (const float*)d_in[0];
  const float* Wq = (const float*)d_in[1];
  const float* Wk = (const float*)d_in[2];
  const float* Wv = (const float*)d_in[3];
  const float* Wo = (const float*)d_in[4];
  float* out = (float*)d_out;
  char* ws = (char*)d_ws;

  // ws layout (bytes):
  unsigned short* xb  = (unsigned short*)(ws);                 // 16 MB
  unsigned short* Wb  = (unsigned short*)(ws + 16777216);      // 4 x 2 MB (q,k,v,o)
  unsigned short* Qb  = (unsigned short*)(ws + 25165824);      // 16 MB
  unsigned short* Kb  = Qb + 8388608;                          // 16 MB @ 41943040
  unsigned short* Vtg = (unsigned short*)(ws + 58720256);      // 16 MB (V^T [bh*64+d][n])
  unsigned short* AO  = (unsigned short*)(ws + 75497472);      // 16 MB
  float* cosT = (float*)(ws + 92274688);                       // 512 KB
  float* sinT = (float*)(ws + 92798976);                       // 512 KB

  // fused prep: x/weight converts + RoPE tables in one dispatch
  k_prep<<<12800, 256, 0, stream>>>(x, Wq, Wk, Wv, Wo, xb, Wb, cosT, sinT);

  // fused Q/K/V projections in ONE kernel (shared A staging, 3 acc streams)
  k_gemm_qkv<<<512, 256, 0, stream>>>(xb, Wb, Qb, Vtg, cosT, sinT);

  // causal flash attention (dual-q-tile shared kv-sweep)
  k_attn15<<<512, 256, 0, stream>>>(Qb, Kb, Vtg, AO);

  // output projection, fp32 out
  k_gemm_bt<<<512, 256, 0, stream>>>(AO, Wb + 3145728, out, DMODEL);
}